// Round 16
// baseline (1068.806 us; speedup 1.0000x reference)
//
#include <hip/hip_runtime.h>

#define B_ 128
#define T_ 100
#define D_ 256
#define H_ 512
#define L_ 40000
#define S_ 10

__device__ __forceinline__ float sigm_(float x){ return 1.f/(1.f + __expf(-x)); }
__device__ __forceinline__ float tanh_(float x){ return 1.f - 2.f/(__expf(2.f*x) + 1.f); }

// 24-bit fixed-point decode: low 24 bits = round(h * 2^23), |h| < 0.762 so it fits.
__device__ __forceinline__ float dec24_(unsigned w){
  int i = ((int)(w << 8)) >> 8;                    // sign-extend 24-bit
  return (float)i * 1.1920928955078125e-7f;        // * 2^-23
}

// ---------------- zero h encoded double-buffer (tag=0, value=0 -> valid for t=0) ----
__global__ void k_zero(unsigned long long* __restrict__ h_enc){
  h_enc[blockIdx.x*256 + threadIdx.x] = 0ull;      // 256 blocks -> 65536 u64 = 2*B*H/2
}

// ---------------- slot projections: Es/Eq = embed @ W_o.T (10 x 512) ----------------
__global__ void k_prep(const float* __restrict__ embed_s, const float* __restrict__ embed_q,
                       const float* __restrict__ w_s, const float* __restrict__ w_q,
                       float* __restrict__ es_proj, float* __restrict__ eq_proj){
  int bid = blockIdx.x;                 // 40 blocks
  int table = bid/20, rem = bid%20, s = rem/2, half = rem%2;
  int jo = half*256 + threadIdx.x;
  const float* emb = (table ? embed_q : embed_s) + s*D_;
  const float* w   = (table ? w_q : w_s) + (size_t)(2*H_ + jo)*D_;   // o-gate rows
  float acc = 0.f;
  #pragma unroll 4
  for (int k=0;k<D_;++k) acc = fmaf(emb[k], w[k], acc);
  (table ? eq_proj : es_proj)[s*H_ + jo] = acc;
}

// ---------------- phase 1: P[t][b][j], j<512 = g-gate preact, j>=512 = o-gate preact ----------------
__global__ __launch_bounds__(256) void k_phase1(
  const int* __restrict__ batch_l, const float* __restrict__ embed_l,
  const float* __restrict__ w_ih, const float* __restrict__ b_ih, const float* __restrict__ b_hh,
  const float* __restrict__ t_ld, const float* __restrict__ t_hd,
  const int* __restrict__ t_l, const int* __restrict__ t_h,
  const float* __restrict__ d_ld, const float* __restrict__ d_hd,
  const int* __restrict__ d_l, const int* __restrict__ d_h,
  const float* __restrict__ es_proj, const float* __restrict__ eq_proj,
  float* __restrict__ P)
{
  __shared__ float As[8][72];
  __shared__ float Bs[8][72];
  __shared__ int ridx[64];
  int mt = blockIdx.x, jt = blockIdx.y;       // 200 x 16
  int t = mt >> 1, b0 = (mt & 1)*64;
  int tid = threadIdx.x;
  if (tid < 64) ridx[tid] = batch_l[(b0+tid)*T_ + t];
  __syncthreads();
  int ty = tid >> 4, tx = tid & 15;
  int r_s = tid >> 2;
  int kk_s = (tid & 3)*2;
  const float* arow = embed_l + (size_t)ridx[r_s]*D_ + kk_s;
  const float* brow = w_ih + (size_t)(2*H_ + jt*64 + r_s)*D_ + kk_s;
  float acc[4][4] = {};
  for (int kc = 0; kc < 32; ++kc) {
    int k0 = kc*8;
    float2 av = *(const float2*)(arow + k0);
    float2 bv = *(const float2*)(brow + k0);
    __syncthreads();
    As[kk_s][r_s] = av.x; As[kk_s+1][r_s] = av.y;
    Bs[kk_s][r_s] = bv.x; Bs[kk_s+1][r_s] = bv.y;
    __syncthreads();
    #pragma unroll
    for (int kk=0;kk<8;++kk){
      float4 a4 = *(const float4*)&As[kk][ty*4];
      float4 b4 = *(const float4*)&Bs[kk][tx*4];
      float avv[4] = {a4.x,a4.y,a4.z,a4.w};
      float bvv[4] = {b4.x,b4.y,b4.z,b4.w};
      #pragma unroll
      for (int i=0;i<4;++i)
        #pragma unroll
        for (int j=0;j<4;++j) acc[i][j] = fmaf(avv[i], bvv[j], acc[i][j]);
    }
  }
  int j0 = jt*64 + tx*4;
  float bias[4];
  #pragma unroll
  for (int j=0;j<4;++j) bias[j] = b_ih[2*H_ + j0 + j] + b_hh[2*H_ + j0 + j];
  #pragma unroll
  for (int i=0;i<4;++i){
    int b = b0 + ty*4 + i;
    size_t m = (size_t)t*B_ + b;
    float add[4] = {0.f,0.f,0.f,0.f};
    if (jt >= 8) {
      int bt = b*T_ + t;
      float dld = d_ld[bt], dhd = d_hd[bt];
      float tld = t_ld[bt], thd = t_hd[bt];
      int dl = d_l[bt], dh = d_h[bt], tl = t_l[bt], th = t_h[bt];
      int jo = j0 - 512;
      #pragma unroll
      for (int j=0;j<4;++j)
        add[j] = dhd*es_proj[dl*H_+jo+j] + dld*es_proj[dh*H_+jo+j]
               + thd*eq_proj[tl*H_+jo+j] + tld*eq_proj[th*H_+jo+j];
    }
    float4 o4;
    o4.x = acc[i][0] + bias[0] + add[0];
    o4.y = acc[i][1] + bias[1] + add[1];
    o4.z = acc[i][2] + bias[2] + add[2];
    o4.w = acc[i][3] + bias[3] + add[3];
    *(float4*)&P[m*1024 + j0] = o4;
  }
}

// ---------------- recurrence: persistent, 256 WGs x 256 thr = 16 bg x 16 js ----------------
// Round-16 = r11's proven shell (697us) with TAG-IN-DATA replacing the flag protocol.
// Each u64 h-slot = [fp32 h(j0+1) | 24-bit-fixed h(j0) + 8-bit step tag]. |h| < tanh(1)
// = 0.7616 so 24-bit fixed (err 6e-8) is exact enough; tag rides free -> SAME 4MB/step
// traffic as r11, but the data IS the signal: no flag store, no flag poll, and only TWO
// barriers/step. The h store moves AFTER the last barrier (producer never waits on its
// own store ACK; consumers poll until it lands).
// Overwrite safety (r5's proof, re-derived): WG X stores h(t+1)[X cols] (overwriting
// same-parity h(t-1)) only after X's stage-poll of h(t) passed, which requires every
// peer Y of the bg to have STORED h(t); Y stores h(t) only after B2 of its iteration
// t-1, which follows Y's complete stage-READ of h(t-1). So no unread data is clobbered.
// Tags in a given parity slot advance by exactly +2 (t-2 -> t -> t+2), so the ==t check
// sees either stale (retry) or fresh, never skips. Tag max = 100 < 256, no wrap.
__global__ __launch_bounds__(256,1) void k_rec(
  const float* __restrict__ w_hh, const float* __restrict__ P,
  unsigned long long* __restrict__ h_enc)
{
  extern __shared__ float sm[];
  float* Wt = sm;                               // [512][66] k-major, r = 4rq+{g0,g1,o0,o1}
  float4* hta = (float4*)(sm + 512*66);         // [512]: h[k][b0..b3]
  float4* htb = hta + 512;                      // [512]: h[k][b4..b7]
  int bid = blockIdx.x;
  int bg = bid & 15, js = bid >> 4;
  int tid = threadIdx.x;
  const float* Wgo = w_hh + (size_t)2*H_*H_;    // rows [0,512)=g, [512,1024)=o
  for (int it=0; it<32; ++it){                  // stage 64x512 weights (r11-exact)
    int e4 = (it*256 + tid)*4;
    int k = e4 & 511, r = e4 >> 9;
    int jh_loc = 2*(r>>2) + (r&1);
    int part = (r>>1)&1;
    int grow = part*H_ + js*32 + jh_loc;
    float4 v = *(const float4*)(Wgo + (size_t)grow*H_ + k);
    Wt[(k+0)*66 + r] = v.x; Wt[(k+1)*66 + r] = v.y;
    Wt[(k+2)*66 + r] = v.z; Wt[(k+3)*66 + r] = v.w;
  }
  int rq = tid >> 4, kq = tid & 15;
  int j0 = js*32 + 2*rq;
  const int gb0 = bg*8;

  // ---- P prefetch for t=0 (lane kq<8 owns batch b=kq)
  float2 pg = {0.f,0.f}, po = {0.f,0.f};
  if (kq < 8){
    size_t prow = (size_t)(gb0 + kq)*1024;
    pg = *(const float2*)&P[prow + j0];
    po = *(const float2*)&P[prow + 512 + j0];
  }

  for (int t=0; t<T_; ++t){
    int par = t & 1;
    // ---- stage h with data-poll: thread tid owns col pair (2tid,2tid+1) for b=0..7
    const unsigned long long* hsrc =
      h_enc + (size_t)par*(B_*H_/2) + (size_t)gb0*(H_/2) + tid;
    unsigned long long v[8];
    #pragma unroll
    for (int b=0;b<8;++b)
      v[b] = __hip_atomic_load(&hsrc[b*(H_/2)], __ATOMIC_RELAXED, __HIP_MEMORY_SCOPE_AGENT);
    unsigned want = (unsigned)t;
    int guard = 0;
    while (true){
      int bad = 0;
      #pragma unroll
      for (int b=0;b<8;++b) bad |= (((unsigned)v[b]) >> 24 != want) ? (1<<b) : 0;
      if (!bad) break;
      if (++guard > (1<<22)) break;             // safety bail (never in normal operation)
      __builtin_amdgcn_s_sleep(1);
      #pragma unroll
      for (int b=0;b<8;++b)
        if (bad & (1<<b))
          v[b] = __hip_atomic_load(&hsrc[b*(H_/2)], __ATOMIC_RELAXED, __HIP_MEMORY_SCOPE_AGENT);
    }
    float a0[8], a1[8];
    #pragma unroll
    for (int b=0;b<8;++b){
      a0[b] = dec24_((unsigned)v[b]);                      // col 2tid (24-bit fixed)
      a1[b] = __uint_as_float((unsigned)(v[b] >> 32));     // col 2tid+1 (fp32)
    }
    hta[2*tid]   = make_float4(a0[0],a0[1],a0[2],a0[3]);
    hta[2*tid+1] = make_float4(a1[0],a1[1],a1[2],a1[3]);
    htb[2*tid]   = make_float4(a0[4],a0[5],a0[6],a0[7]);
    htb[2*tid+1] = make_float4(a1[4],a1[5],a1[6],a1[7]);
    __syncthreads();                            // B1: staged LDS visible

    // ---- compute: acc[r][b] = sum over k-slice (k = kk*16+kq) of w[r][k]*h[k][b]
    float acc[4][8] = {};
    #pragma unroll 4
    for (int kk=0; kk<32; ++kk){
      int k = kk*16 + kq;
      float2 wA = *(const float2*)&Wt[k*66 + 4*rq];
      float2 wB = *(const float2*)&Wt[k*66 + 4*rq + 2];
      float4 ha = hta[k];
      float4 hb = htb[k];
      float hvv[8] = {ha.x,ha.y,ha.z,ha.w,hb.x,hb.y,hb.z,hb.w};
      #pragma unroll
      for (int i=0;i<8;++i){
        acc[0][i] = fmaf(wA.x, hvv[i], acc[0][i]);
        acc[1][i] = fmaf(wA.y, hvv[i], acc[1][i]);
        acc[2][i] = fmaf(wB.x, hvv[i], acc[2][i]);
        acc[3][i] = fmaf(wB.y, hvv[i], acc[3][i]);
      }
    }
    // ---- butterfly reduce over the 16-lane kq groups
    #pragma unroll
    for (int r=0;r<4;++r)
      #pragma unroll
      for (int i=0;i<8;++i){
        float s = acc[r][i];
        s += __shfl_xor(s, 1, 64);
        s += __shfl_xor(s, 2, 64);
        s += __shfl_xor(s, 4, 64);
        s += __shfl_xor(s, 8, 64);
        acc[r][i] = s;
      }
    __syncthreads();   // B2: all LDS reads done; cheap (no pending vmem of ours)

    // ---- epilogue AFTER barrier: encode + fire-and-forget store; consumers poll
    if (kq < 8){
      int b = kq;
      float gg0 = acc[0][b] + pg.x, gg1 = acc[1][b] + pg.y;
      float oo0 = acc[2][b] + po.x, oo1 = acc[3][b] + po.y;
      float h0 = sigm_(oo0)*tanh_(tanh_(gg0));          // |h| < tanh(1)
      float h1 = sigm_(oo1)*tanh_(tanh_(gg1));
      unsigned lo = ((unsigned)__float2int_rn(h0 * 8388608.f) & 0xFFFFFFu)
                  | ((unsigned)(t+1) << 24);
      unsigned long long u = (unsigned long long)lo
                           | ((unsigned long long)__float_as_uint(h1) << 32);
      __hip_atomic_store(
        h_enc + (size_t)(1-par)*(B_*H_/2) + (size_t)(gb0 + b)*(H_/2) + (j0 >> 1),
        u, __ATOMIC_RELAXED, __HIP_MEMORY_SCOPE_AGENT);
      if (t+1 < T_){   // prefetch next step's P in the store shadow
        size_t prow = ((size_t)(t+1)*B_ + gb0 + b)*1024;
        pg = *(const float2*)&P[prow + j0];
        po = *(const float2*)&P[prow + 512 + j0];
      }
    }
  }
}

// ---------------- classifier: out = hT @ w_out.T + b_out (hT = parity-0 h_enc) -------
__global__ __launch_bounds__(256) void k_cls(
  const unsigned long long* __restrict__ h_enc, const float* __restrict__ w_out,
  const float* __restrict__ b_out, float* __restrict__ out)
{
  __shared__ float wt[32*68];     // [k][l] k-major
  __shared__ float htl[32*132];   // [k][b]
  int l0 = blockIdx.x * 64;       // 625 blocks
  int tid = threadIdx.x;
  int lq = tid >> 4, bq = tid & 15;
  float acc[4][8] = {};
  for (int kc=0; kc<16; ++kc){
    int k0 = kc*32;
    __syncthreads();
    #pragma unroll
    for (int it=0; it<2; ++it){   // w_out tile via float4 (coalesced 16B/lane)
      int f = it*256 + tid;       // 0..511
      int l = f >> 3, k4 = (f & 7)*4;
      float4 v = *(const float4*)&w_out[(size_t)(l0+l)*H_ + k0 + k4];
      wt[(k4+0)*68 + l] = v.x; wt[(k4+1)*68 + l] = v.y;
      wt[(k4+2)*68 + l] = v.z; wt[(k4+3)*68 + l] = v.w;
    }
    #pragma unroll
    for (int it=0; it<4; ++it){   // hT tile via uint4 (2 u64 = 4 cols) + decode
      int f = it*256 + tid;       // 0..1023
      int b = f >> 3, k4 = (f & 7)*4;
      uint4 v = *(const uint4*)&h_enc[(size_t)b*(H_/2) + ((k0 + k4) >> 1)];
      htl[(k4+0)*132 + b] = dec24_(v.x);
      htl[(k4+1)*132 + b] = __uint_as_float(v.y);
      htl[(k4+2)*132 + b] = dec24_(v.z);
      htl[(k4+3)*132 + b] = __uint_as_float(v.w);
    }
    __syncthreads();
    #pragma unroll 4
    for (int k=0;k<32;++k){
      float4 w4 = *(const float4*)&wt[k*68 + lq*4];
      float4 h0 = *(const float4*)&htl[k*132 + bq*8];
      float4 h1 = *(const float4*)&htl[k*132 + bq*8 + 4];
      float wv[4] = {w4.x,w4.y,w4.z,w4.w};
      float hv[8] = {h0.x,h0.y,h0.z,h0.w,h1.x,h1.y,h1.z,h1.w};
      #pragma unroll
      for (int m=0;m<4;++m)
        #pragma unroll
        for (int i=0;i<8;++i) acc[m][i] = fmaf(wv[m], hv[i], acc[m][i]);
    }
  }
  int l = l0 + lq*4;
  float4 bo = *(const float4*)&b_out[l];
  #pragma unroll
  for (int i=0;i<8;++i){
    int b = bq*8 + i;
    float4 o4;
    o4.x = acc[0][i] + bo.x; o4.y = acc[1][i] + bo.y;
    o4.z = acc[2][i] + bo.z; o4.w = acc[3][i] + bo.w;
    *(float4*)&out[(size_t)b*L_ + l] = o4;
  }
}

extern "C" void kernel_launch(void* const* d_in, const int* in_sizes, int n_in,
                              void* d_out, int out_size, void* d_ws, size_t ws_size,
                              hipStream_t stream) {
  const int*   batch_l = (const int*)  d_in[0];
  const float* t_ld    = (const float*)d_in[1];
  const float* t_hd    = (const float*)d_in[2];
  const int*   t_l     = (const int*)  d_in[3];
  const int*   t_h     = (const int*)  d_in[4];
  const float* d_ld    = (const float*)d_in[5];
  const float* d_hd    = (const float*)d_in[6];
  const int*   d_l     = (const int*)  d_in[7];
  const int*   d_h     = (const int*)  d_in[8];
  const float* embed_l = (const float*)d_in[9];
  const float* embed_s = (const float*)d_in[10];
  const float* embed_q = (const float*)d_in[11];
  const float* w_ih    = (const float*)d_in[12];
  const float* w_hh    = (const float*)d_in[13];
  const float* w_s     = (const float*)d_in[14];
  const float* w_q     = (const float*)d_in[15];
  const float* b_ih    = (const float*)d_in[16];
  const float* b_hh    = (const float*)d_in[17];
  const float* w_out   = (const float*)d_in[18];
  const float* b_out   = (const float*)d_in[19];
  float* out = (float*)d_out;

  // workspace layout (float offsets; h_enc is u64, offset even -> 8B/16B aligned)
  float* ws = (float*)d_ws;
  const size_t P_off  = 0;                          // 13107200 f
  const size_t h_off  = 13107200;                   // 131072 f = 65536 u64 (2 parities)
  const size_t es_off = h_off + 131072;             // 5120 f
  const size_t eq_off = es_off + 5120;              // 5120 f
  const size_t need_bytes = (eq_off + 5120)*4 + 64;
  if (ws_size < need_bytes) return;

  float* P = ws + P_off;
  unsigned long long* h_enc = (unsigned long long*)(ws + h_off);
  float* es_proj = ws + es_off;
  float* eq_proj = ws + eq_off;

  hipFuncSetAttribute(reinterpret_cast<const void*>(k_rec),
                      hipFuncAttributeMaxDynamicSharedMemorySize, 151552);

  k_zero<<<256, 256, 0, stream>>>(h_enc);
  k_prep<<<40, 256, 0, stream>>>(embed_s, embed_q, w_s, w_q, es_proj, eq_proj);
  k_phase1<<<dim3(200,16), 256, 0, stream>>>(batch_l, embed_l, w_ih, b_ih, b_hh,
      t_ld, t_hd, t_l, t_h, d_ld, d_hd, d_l, d_h, es_proj, eq_proj, P);
  k_rec<<<256, 256, 151552, stream>>>(w_hh, P, h_enc);
  k_cls<<<625, 256, 0, stream>>>(h_enc, w_out, b_out, out);
}

// Round 17
// 920.975 us; speedup vs baseline: 1.1605x; 1.1605x over previous
//
#include <hip/hip_runtime.h>

#define B_ 128
#define T_ 100
#define D_ 256
#define H_ 512
#define L_ 40000
#define S_ 10

__device__ __forceinline__ float sigm_(float x){ return 1.f/(1.f + __expf(-x)); }
__device__ __forceinline__ float tanh_(float x){ return 1.f - 2.f/(__expf(2.f*x) + 1.f); }

union F2U64 { float2 f; unsigned long long u; };

typedef __attribute__((ext_vector_type(8))) short bf16x8;
typedef __attribute__((ext_vector_type(4))) float f32x4;

// RNE fp32 -> bf16 (as ushort)
__device__ __forceinline__ unsigned short bfhi_(float x){
  unsigned u = __float_as_uint(x);
  return (unsigned short)((u + 0x7FFFu + ((u >> 16) & 1u)) >> 16);
}
__device__ __forceinline__ float bf2f_(unsigned short h){
  return __uint_as_float(((unsigned)h) << 16);
}

// ---------------- zero h double-buffer + flags ----------------
__global__ void k_zero(float* __restrict__ h_buf, unsigned* __restrict__ flags){
  int idx = blockIdx.x*256 + threadIdx.x;
  if (blockIdx.x < 512) h_buf[idx] = 0.f;               // 2*B*H floats
  else if (threadIdx.x < 256) flags[threadIdx.x] = 0u;  // 256 u32 (16 bg x 16 js)
}

// ---------------- slot projections: Es/Eq = embed @ W_o.T (10 x 512) ----------------
__global__ void k_prep(const float* __restrict__ embed_s, const float* __restrict__ embed_q,
                       const float* __restrict__ w_s, const float* __restrict__ w_q,
                       float* __restrict__ es_proj, float* __restrict__ eq_proj){
  int bid = blockIdx.x;                 // 40 blocks
  int table = bid/20, rem = bid%20, s = rem/2, half = rem%2;
  int jo = half*256 + threadIdx.x;
  const float* emb = (table ? embed_q : embed_s) + s*D_;
  const float* w   = (table ? w_q : w_s) + (size_t)(2*H_ + jo)*D_;   // o-gate rows
  float acc = 0.f;
  #pragma unroll 4
  for (int k=0;k<D_;++k) acc = fmaf(emb[k], w[k], acc);
  (table ? eq_proj : es_proj)[s*H_ + jo] = acc;
}

// ---------------- phase 1 (MFMA, split-bf16): P[t][b][j] --------------------------
// C[M=12800][N=1024] = A[M][256] * B[N][256]^T with A = gathered embed_l rows,
// B = w_ih rows 2H..4H (g then o). Split-precision: x = hi + lo (both bf16, lo exact
// residual), accumulate x_hi*w_hi + x_hi*w_lo + x_lo*w_hi in fp32 MFMA -> rel err ~2^-17.
// Tile 64x64, full K in LDS as 4 bf16 tiles [64][264] (row stride 528B: b128 frag reads
// land on distinct bank quads). 4 waves; wave w owns M-rows w*16..+15; 4 N-frags each.
// Fragment mapping (guide m89/m91, verified): A lane: row=l&15, k=(l>>4)*8+e;
// B^T lane: col=l&15, same k; D: col=l&15, row=(l>>4)*4+reg.
__global__ __launch_bounds__(256,1) void k_phase1(
  const int* __restrict__ batch_l, const float* __restrict__ embed_l,
  const float* __restrict__ w_ih, const float* __restrict__ b_ih, const float* __restrict__ b_hh,
  const float* __restrict__ t_ld, const float* __restrict__ t_hd,
  const int* __restrict__ t_l, const int* __restrict__ t_h,
  const float* __restrict__ d_ld, const float* __restrict__ d_hd,
  const int* __restrict__ d_l, const int* __restrict__ d_h,
  const float* __restrict__ es_proj, const float* __restrict__ eq_proj,
  float* __restrict__ P)
{
  extern __shared__ char smraw[];
  unsigned short* Ahi = (unsigned short*)smraw;          // [64][264]
  unsigned short* Alo = Ahi + 64*264;
  unsigned short* Bhi = Alo + 64*264;
  unsigned short* Blo = Bhi + 64*264;
  int* ridx = (int*)(Blo + 64*264);                      // [64]
  int mt = blockIdx.x, jt = blockIdx.y;                  // 200 x 16
  int t = mt >> 1, b0 = (mt & 1)*64;
  int tid = threadIdx.x;
  if (tid < 64) ridx[tid] = batch_l[(b0+tid)*T_ + t];
  __syncthreads();

  // ---- stage A (embed gathers) and B (w_ih rows) as bf16 hi/lo
  #pragma unroll
  for (int it=0; it<16; ++it){
    int idx = it*256 + tid;            // 0..4095 float4 slots
    int m = idx >> 6, k4 = (idx & 63)*4;
    float4 av = *(const float4*)(embed_l + (size_t)ridx[m]*D_ + k4);
    ushort4 hi, lo;
    hi.x = bfhi_(av.x); lo.x = bfhi_(av.x - bf2f_(hi.x));
    hi.y = bfhi_(av.y); lo.y = bfhi_(av.y - bf2f_(hi.y));
    hi.z = bfhi_(av.z); lo.z = bfhi_(av.z - bf2f_(hi.z));
    hi.w = bfhi_(av.w); lo.w = bfhi_(av.w - bf2f_(hi.w));
    *(ushort4*)&Ahi[m*264 + k4] = hi;
    *(ushort4*)&Alo[m*264 + k4] = lo;
    float4 bv = *(const float4*)(w_ih + (size_t)(2*H_ + jt*64 + m)*D_ + k4);
    hi.x = bfhi_(bv.x); lo.x = bfhi_(bv.x - bf2f_(hi.x));
    hi.y = bfhi_(bv.y); lo.y = bfhi_(bv.y - bf2f_(hi.y));
    hi.z = bfhi_(bv.z); lo.z = bfhi_(bv.z - bf2f_(hi.z));
    hi.w = bfhi_(bv.w); lo.w = bfhi_(bv.w - bf2f_(hi.w));
    *(ushort4*)&Bhi[m*264 + k4] = hi;
    *(ushort4*)&Blo[m*264 + k4] = lo;
  }
  __syncthreads();

  // ---- MFMA compute
  int lane = tid & 63, wv = tid >> 6;
  int ar = lane & 15, kb = lane >> 4;
  int mw = wv*16;
  f32x4 acc0 = {0.f,0.f,0.f,0.f}, acc1 = {0.f,0.f,0.f,0.f};
  f32x4 acc2 = {0.f,0.f,0.f,0.f}, acc3 = {0.f,0.f,0.f,0.f};
  const unsigned short* aph = Ahi + (mw + ar)*264 + kb*8;
  const unsigned short* apl = Alo + (mw + ar)*264 + kb*8;
  const unsigned short* bph = Bhi + ar*264 + kb*8;
  const unsigned short* bpl = Blo + ar*264 + kb*8;
  #pragma unroll
  for (int kc=0; kc<8; ++kc){
    bf16x8 a_hi = *(const bf16x8*)(aph + kc*32);
    bf16x8 a_lo = *(const bf16x8*)(apl + kc*32);
    #pragma unroll
    for (int nf=0; nf<4; ++nf){
      bf16x8 b_hi = *(const bf16x8*)(bph + nf*16*264 + kc*32);
      bf16x8 b_lo = *(const bf16x8*)(bpl + nf*16*264 + kc*32);
      f32x4 a = (nf==0)?acc0:(nf==1)?acc1:(nf==2)?acc2:acc3;
      a = __builtin_amdgcn_mfma_f32_16x16x32_bf16(a_hi, b_hi, a, 0, 0, 0);
      a = __builtin_amdgcn_mfma_f32_16x16x32_bf16(a_hi, b_lo, a, 0, 0, 0);
      a = __builtin_amdgcn_mfma_f32_16x16x32_bf16(a_lo, b_hi, a, 0, 0, 0);
      if (nf==0) acc0=a; else if (nf==1) acc1=a; else if (nf==2) acc2=a; else acc3=a;
    }
  }

  // ---- epilogue: bias + (jt>=8) slot interpolation, D mapping col=l&15,row=(l>>4)*4+r
  float bias[4];
  #pragma unroll
  for (int nf=0; nf<4; ++nf){
    int j = jt*64 + nf*16 + ar;
    bias[nf] = b_ih[2*H_ + j] + b_hh[2*H_ + j];
  }
  #pragma unroll
  for (int r=0; r<4; ++r){
    int b = b0 + mw + kb*4 + r;
    float dldv=0.f, dhdv=0.f, tldv=0.f, thdv=0.f;
    int dlv=0, dhv=0, tlv=0, thv=0;
    if (jt >= 8){
      int bt = b*T_ + t;
      dldv=d_ld[bt]; dhdv=d_hd[bt]; tldv=t_ld[bt]; thdv=t_hd[bt];
      dlv=d_l[bt]; dhv=d_h[bt]; tlv=t_l[bt]; thv=t_h[bt];
    }
    #pragma unroll
    for (int nf=0; nf<4; ++nf){
      int j = jt*64 + nf*16 + ar;
      float v = ((nf==0)?acc0[r]:(nf==1)?acc1[r]:(nf==2)?acc2[r]:acc3[r]) + bias[nf];
      if (jt >= 8){
        int jo = j - 512;
        v += dhdv*es_proj[dlv*H_+jo] + dldv*es_proj[dhv*H_+jo]
           + thdv*eq_proj[tlv*H_+jo] + tldv*eq_proj[thv*H_+jo];
      }
      P[((size_t)t*B_ + b)*1024 + j] = v;
    }
  }
}

// ---------------- recurrence: persistent, 256 WGs x 256 thr = 16 bg x 16 js ----------------
// r11-EXACT (697us proven): LDS weights, float4 h LDS tiles, u64 relaxed-atomic h
// exchange, per-WG flag stores on one 64B line/bg polled by 16 lanes.
__global__ __launch_bounds__(256,1) void k_rec(
  const float* __restrict__ w_hh, const float* __restrict__ P,
  float* __restrict__ h_buf, unsigned* __restrict__ flags)
{
  extern __shared__ float sm[];
  float* Wt = sm;                               // [512][66] k-major, r = 4rq+{g0,g1,o0,o1}
  float4* hta = (float4*)(sm + 512*66);         // [512]: h[k][b0..b3]
  float4* htb = hta + 512;                      // [512]: h[k][b4..b7]
  int bid = blockIdx.x;
  int bg = bid & 15, js = bid >> 4;
  int tid = threadIdx.x;
  const float* Wgo = w_hh + (size_t)2*H_*H_;    // rows [0,512)=g, [512,1024)=o
  for (int it=0; it<32; ++it){                  // stage 64x512 weights
    int e4 = (it*256 + tid)*4;
    int k = e4 & 511, r = e4 >> 9;
    int jh_loc = 2*(r>>2) + (r&1);
    int part = (r>>1)&1;
    int grow = part*H_ + js*32 + jh_loc;
    float4 v = *(const float4*)(Wgo + (size_t)grow*H_ + k);
    Wt[(k+0)*66 + r] = v.x; Wt[(k+1)*66 + r] = v.y;
    Wt[(k+2)*66 + r] = v.z; Wt[(k+3)*66 + r] = v.w;
  }
  int rq = tid >> 4, kq = tid & 15;
  int j0 = js*32 + 2*rq;
  const int gb0 = bg*8;
  unsigned* bgflags = flags + bg*16;            // 16 u32 in one 64B line

  float2 pg = {0.f,0.f}, po = {0.f,0.f};
  if (kq < 8){
    size_t prow = (size_t)(gb0 + kq)*1024;
    pg = *(const float2*)&P[prow + j0];
    po = *(const float2*)&P[prow + 512 + j0];
  }
  __syncthreads();                              // weights staged

  for (int t=0; t<T_; ++t){
    int par = t & 1;
    if (t > 0){
      if (tid < 16){                            // one coalesced 64B line read per poll
        unsigned* f = bgflags + tid;
        int guard = 0;
        while (__hip_atomic_load(f, __ATOMIC_RELAXED, __HIP_MEMORY_SCOPE_AGENT) < (unsigned)t){
          __builtin_amdgcn_s_sleep(4);
          if (++guard > (1<<22)) break;         // safety bail (never in normal operation)
        }
      }
      __syncthreads();
    }
    // ---- stage h: thread tid loads u64 pair (k=2tid, 2tid+1) for b=0..7
    const unsigned long long* hsrc =
      (const unsigned long long*)(h_buf + (size_t)par*(B_*H_) + (size_t)gb0*H_) + tid;
    F2U64 v[8];
    #pragma unroll
    for (int b=0;b<8;++b)
      v[b].u = __hip_atomic_load(&hsrc[b*(H_/2)], __ATOMIC_RELAXED, __HIP_MEMORY_SCOPE_AGENT);
    hta[2*tid]   = make_float4(v[0].f.x, v[1].f.x, v[2].f.x, v[3].f.x);
    hta[2*tid+1] = make_float4(v[0].f.y, v[1].f.y, v[2].f.y, v[3].f.y);
    htb[2*tid]   = make_float4(v[4].f.x, v[5].f.x, v[6].f.x, v[7].f.x);
    htb[2*tid+1] = make_float4(v[4].f.y, v[5].f.y, v[6].f.y, v[7].f.y);
    __syncthreads();

    // ---- compute: acc[r][b] = sum over k-slice (k = kk*16+kq) of w[r][k]*h[k][b]
    float acc[4][8] = {};
    #pragma unroll 4
    for (int kk=0; kk<32; ++kk){
      int k = kk*16 + kq;
      float2 wA = *(const float2*)&Wt[k*66 + 4*rq];
      float2 wB = *(const float2*)&Wt[k*66 + 4*rq + 2];
      float4 ha = hta[k];
      float4 hb = htb[k];
      float hvv[8] = {ha.x,ha.y,ha.z,ha.w,hb.x,hb.y,hb.z,hb.w};
      #pragma unroll
      for (int i=0;i<8;++i){
        acc[0][i] = fmaf(wA.x, hvv[i], acc[0][i]);
        acc[1][i] = fmaf(wA.y, hvv[i], acc[1][i]);
        acc[2][i] = fmaf(wB.x, hvv[i], acc[2][i]);
        acc[3][i] = fmaf(wB.y, hvv[i], acc[3][i]);
      }
    }
    // ---- butterfly reduce over the 16-lane kq groups
    #pragma unroll
    for (int r=0;r<4;++r)
      #pragma unroll
      for (int i=0;i<8;++i){
        float s = acc[r][i];
        s += __shfl_xor(s, 1, 64);
        s += __shfl_xor(s, 2, 64);
        s += __shfl_xor(s, 4, 64);
        s += __shfl_xor(s, 8, 64);
        acc[r][i] = s;
      }
    // ---- epilogue: lane kq=b (b<8) stores h(j0),h(j0+1) for batch b as one u64 atomic
    if (kq < 8){
      int b = kq;
      float gg0 = acc[0][b] + pg.x, gg1 = acc[1][b] + pg.y;
      float oo0 = acc[2][b] + po.x, oo1 = acc[3][b] + po.y;
      F2U64 h2;
      h2.f.x = sigm_(oo0)*tanh_(tanh_(gg0));
      h2.f.y = sigm_(oo1)*tanh_(tanh_(gg1));
      __hip_atomic_store((unsigned long long*)
        (h_buf + (size_t)(1-par)*(B_*H_) + (size_t)(gb0 + b)*H_ + j0),
        h2.u, __ATOMIC_RELAXED, __HIP_MEMORY_SCOPE_AGENT);
    }
    __syncthreads();   // per-wave vmcnt(0): h loads consumed AND h stores visible
    if (t+1 < T_){
      if (tid == 0)
        __hip_atomic_store(bgflags + js, (unsigned)(t+1),
                           __ATOMIC_RELAXED, __HIP_MEMORY_SCOPE_AGENT);
      if (kq < 8){   // prefetch next step's P; overlaps peers' completion
        size_t prow = ((size_t)(t+1)*B_ + gb0 + kq)*1024;
        pg = *(const float2*)&P[prow + j0];
        po = *(const float2*)&P[prow + 512 + j0];
      }
    }
  }
}

// ---------------- classifier: out = hT @ w_out.T + b_out ----------------
__global__ __launch_bounds__(256) void k_cls(
  const float* __restrict__ hT, const float* __restrict__ w_out,
  const float* __restrict__ b_out, float* __restrict__ out)
{
  __shared__ float wt[32*68];     // [k][l] k-major
  __shared__ float htl[32*132];   // [k][b]
  int l0 = blockIdx.x * 64;       // 625 blocks
  int tid = threadIdx.x;
  int lq = tid >> 4, bq = tid & 15;
  float acc[4][8] = {};
  for (int kc=0; kc<16; ++kc){
    int k0 = kc*32;
    __syncthreads();
    for (int it=0; it<8; ++it){
      int e = it*256 + tid; int k = e & 31, l = e >> 5;
      wt[k*68 + l] = w_out[(size_t)(l0+l)*H_ + k0 + k];
    }
    for (int it=0; it<16; ++it){
      int e = it*256 + tid; int k = e & 31, b = e >> 5;
      htl[k*132 + b] = hT[(size_t)b*H_ + k0 + k];
    }
    __syncthreads();
    #pragma unroll 4
    for (int k=0;k<32;++k){
      float4 w4 = *(const float4*)&wt[k*68 + lq*4];
      float4 h0 = *(const float4*)&htl[k*132 + bq*8];
      float4 h1 = *(const float4*)&htl[k*132 + bq*8 + 4];
      float wv[4] = {w4.x,w4.y,w4.z,w4.w};
      float hv[8] = {h0.x,h0.y,h0.z,h0.w,h1.x,h1.y,h1.z,h1.w};
      #pragma unroll
      for (int m=0;m<4;++m)
        #pragma unroll
        for (int i=0;i<8;++i) acc[m][i] = fmaf(wv[m], hv[i], acc[m][i]);
    }
  }
  int l = l0 + lq*4;
  float4 bo = *(const float4*)&b_out[l];
  #pragma unroll
  for (int i=0;i<8;++i){
    int b = bq*8 + i;
    float4 o4;
    o4.x = acc[0][i] + bo.x; o4.y = acc[1][i] + bo.y;
    o4.z = acc[2][i] + bo.z; o4.w = acc[3][i] + bo.w;
    *(float4*)&out[(size_t)b*L_ + l] = o4;
  }
}

extern "C" void kernel_launch(void* const* d_in, const int* in_sizes, int n_in,
                              void* d_out, int out_size, void* d_ws, size_t ws_size,
                              hipStream_t stream) {
  const int*   batch_l = (const int*)  d_in[0];
  const float* t_ld    = (const float*)d_in[1];
  const float* t_hd    = (const float*)d_in[2];
  const int*   t_l     = (const int*)  d_in[3];
  const int*   t_h     = (const int*)  d_in[4];
  const float* d_ld    = (const float*)d_in[5];
  const float* d_hd    = (const float*)d_in[6];
  const int*   d_l     = (const int*)  d_in[7];
  const int*   d_h     = (const int*)  d_in[8];
  const float* embed_l = (const float*)d_in[9];
  const float* embed_s = (const float*)d_in[10];
  const float* embed_q = (const float*)d_in[11];
  const float* w_ih    = (const float*)d_in[12];
  const float* w_hh    = (const float*)d_in[13];
  const float* w_s     = (const float*)d_in[14];
  const float* w_q     = (const float*)d_in[15];
  const float* b_ih    = (const float*)d_in[16];
  const float* b_hh    = (const float*)d_in[17];
  const float* w_out   = (const float*)d_in[18];
  const float* b_out   = (const float*)d_in[19];
  float* out = (float*)d_out;

  // workspace layout (float offsets)
  float* ws = (float*)d_ws;
  const size_t P_off   = 0;                         // 13107200 f
  const size_t h_off   = 13107200;                  // 131072 f (2*B*H double buffer)
  const size_t es_off  = h_off + 131072;            // 5120 f
  const size_t eq_off  = es_off + 5120;             // 5120 f
  const size_t flg_off = eq_off + 5120;             // 256 u32 (16 bg x 16 js, 64B/bg)
  const size_t need_bytes = (flg_off + 256)*4 + 64;
  if (ws_size < need_bytes) return;

  float* P        = ws + P_off;
  float* h_buf    = ws + h_off;
  float* es_proj  = ws + es_off;
  float* eq_proj  = ws + eq_off;
  unsigned* flags = (unsigned*)(ws + flg_off);

  hipFuncSetAttribute(reinterpret_cast<const void*>(k_rec),
                      hipFuncAttributeMaxDynamicSharedMemorySize, 151552);
  hipFuncSetAttribute(reinterpret_cast<const void*>(k_phase1),
                      hipFuncAttributeMaxDynamicSharedMemorySize, 135424);

  k_zero<<<513, 256, 0, stream>>>(h_buf, flags);
  k_prep<<<40, 256, 0, stream>>>(embed_s, embed_q, w_s, w_q, es_proj, eq_proj);
  k_phase1<<<dim3(200,16), 256, 135424, stream>>>(batch_l, embed_l, w_ih, b_ih, b_hh,
      t_ld, t_hd, t_l, t_h, d_ld, d_hd, d_l, d_h, es_proj, eq_proj, P);
  k_rec<<<256, 256, 151552, stream>>>(w_hh, P, h_buf, flags);
  k_cls<<<625, 256, 0, stream>>>(h_buf, w_out, b_out, out);
}

// Round 18
// 902.841 us; speedup vs baseline: 1.1838x; 1.0201x over previous
//
#include <hip/hip_runtime.h>

#define B_ 128
#define T_ 100
#define D_ 256
#define H_ 512
#define L_ 40000
#define S_ 10

__device__ __forceinline__ float sigm_(float x){ return 1.f/(1.f + __expf(-x)); }
__device__ __forceinline__ float tanh_(float x){ return 1.f - 2.f/(__expf(2.f*x) + 1.f); }

union F2U64 { float2 f; unsigned long long u; };

typedef __attribute__((ext_vector_type(8))) short bf16x8;
typedef __attribute__((ext_vector_type(4))) float f32x4;

// RNE fp32 -> bf16 (as ushort)
__device__ __forceinline__ unsigned short bfhi_(float x){
  unsigned u = __float_as_uint(x);
  return (unsigned short)((u + 0x7FFFu + ((u >> 16) & 1u)) >> 16);
}
__device__ __forceinline__ float bf2f_(unsigned short h){
  return __uint_as_float(((unsigned)h) << 16);
}

// ---------------- zero h double-buffer + flags ----------------
__global__ void k_zero(float* __restrict__ h_buf, unsigned* __restrict__ flags){
  int idx = blockIdx.x*256 + threadIdx.x;
  if (blockIdx.x < 512) h_buf[idx] = 0.f;               // 2*B*H floats
  else if (threadIdx.x < 256) flags[threadIdx.x] = 0u;  // 256 u32 (16 bg x 16 js)
}

// ---------------- slot projections: Es/Eq = embed @ W_o.T (10 x 512) ----------------
__global__ void k_prep(const float* __restrict__ embed_s, const float* __restrict__ embed_q,
                       const float* __restrict__ w_s, const float* __restrict__ w_q,
                       float* __restrict__ es_proj, float* __restrict__ eq_proj){
  int bid = blockIdx.x;                 // 40 blocks
  int table = bid/20, rem = bid%20, s = rem/2, half = rem%2;
  int jo = half*256 + threadIdx.x;
  const float* emb = (table ? embed_q : embed_s) + s*D_;
  const float* w   = (table ? w_q : w_s) + (size_t)(2*H_ + jo)*D_;   // o-gate rows
  float acc = 0.f;
  #pragma unroll 4
  for (int k=0;k<D_;++k) acc = fmaf(emb[k], w[k], acc);
  (table ? eq_proj : es_proj)[s*H_ + jo] = acc;
}

// ---------------- one-time bf16 hi/lo conversion of embed_l and w_ih g/o rows ------
// Ehi/Elo: [40000][256] ushort; Whi/Wlo: [1024][256] ushort (w_ih rows 2H..4H).
__global__ __launch_bounds__(256) void k_conv(
  const float* __restrict__ embed_l, const float* __restrict__ w_ih,
  unsigned short* __restrict__ Ehi, unsigned short* __restrict__ Elo,
  unsigned short* __restrict__ Whi, unsigned short* __restrict__ Wlo)
{
  long long g = (long long)blockIdx.x*256 + threadIdx.x;   // float4 group index
  const float* src;
  unsigned short *dhi, *dlo;
  size_t off;
  if (g < 2560000LL){                    // embed: 40000*64 groups
    off = (size_t)g*4;
    src = embed_l + off;
    dhi = Ehi + off; dlo = Elo + off;
  } else {
    long long g2 = g - 2560000LL;        // w: 1024*64 groups
    if (g2 >= 65536LL) return;
    size_t row = (size_t)(g2 >> 6), k4 = (size_t)(g2 & 63)*4;
    src = w_ih + (2*H_ + row)*D_ + k4;
    off = row*D_ + k4;
    dhi = Whi + off; dlo = Wlo + off;
  }
  float4 v = *(const float4*)src;
  ushort4 hi, lo;
  hi.x = bfhi_(v.x); lo.x = bfhi_(v.x - bf2f_(hi.x));
  hi.y = bfhi_(v.y); lo.y = bfhi_(v.y - bf2f_(hi.y));
  hi.z = bfhi_(v.z); lo.z = bfhi_(v.z - bf2f_(hi.z));
  hi.w = bfhi_(v.w); lo.w = bfhi_(v.w - bf2f_(hi.w));
  *(ushort4*)dhi = hi;
  *(ushort4*)dlo = lo;
}

// ---------------- phase 1 (MFMA, pre-converted bf16, LDS-free) ----------------------
// Same math/mapping as r17's PASSING kernel (absmax 4.88e-4); fragments now load
// directly from the pre-converted global arrays (L2-hot). LDS = ridx only -> high
// occupancy, no staging conversion, no tile barriers.
__global__ __launch_bounds__(256) void k_phase1(
  const int* __restrict__ batch_l,
  const unsigned short* __restrict__ Ehi, const unsigned short* __restrict__ Elo,
  const unsigned short* __restrict__ Whi, const unsigned short* __restrict__ Wlo,
  const float* __restrict__ b_ih, const float* __restrict__ b_hh,
  const float* __restrict__ t_ld, const float* __restrict__ t_hd,
  const int* __restrict__ t_l, const int* __restrict__ t_h,
  const float* __restrict__ d_ld, const float* __restrict__ d_hd,
  const int* __restrict__ d_l, const int* __restrict__ d_h,
  const float* __restrict__ es_proj, const float* __restrict__ eq_proj,
  float* __restrict__ P)
{
  __shared__ int ridx[64];
  int mt = blockIdx.x, jt = blockIdx.y;                  // 200 x 16
  int t = mt >> 1, b0 = (mt & 1)*64;
  int tid = threadIdx.x;
  if (tid < 64) ridx[tid] = batch_l[(b0+tid)*T_ + t];
  __syncthreads();

  int lane = tid & 63, wv = tid >> 6;
  int ar = lane & 15, kb = lane >> 4;
  int mw = wv*16;
  f32x4 acc0 = {0.f,0.f,0.f,0.f}, acc1 = {0.f,0.f,0.f,0.f};
  f32x4 acc2 = {0.f,0.f,0.f,0.f}, acc3 = {0.f,0.f,0.f,0.f};
  const size_t arow = (size_t)ridx[mw + ar]*D_ + kb*8;
  const size_t brow0 = (size_t)(jt*64 + ar)*D_ + kb*8;   // nf adds 16*D_
  #pragma unroll
  for (int kc=0; kc<8; ++kc){
    bf16x8 a_hi = *(const bf16x8*)(Ehi + arow + kc*32);
    bf16x8 a_lo = *(const bf16x8*)(Elo + arow + kc*32);
    #pragma unroll
    for (int nf=0; nf<4; ++nf){
      bf16x8 b_hi = *(const bf16x8*)(Whi + brow0 + (size_t)nf*16*D_ + kc*32);
      bf16x8 b_lo = *(const bf16x8*)(Wlo + brow0 + (size_t)nf*16*D_ + kc*32);
      f32x4 a = (nf==0)?acc0:(nf==1)?acc1:(nf==2)?acc2:acc3;
      a = __builtin_amdgcn_mfma_f32_16x16x32_bf16(a_hi, b_hi, a, 0, 0, 0);
      a = __builtin_amdgcn_mfma_f32_16x16x32_bf16(a_hi, b_lo, a, 0, 0, 0);
      a = __builtin_amdgcn_mfma_f32_16x16x32_bf16(a_lo, b_hi, a, 0, 0, 0);
      if (nf==0) acc0=a; else if (nf==1) acc1=a; else if (nf==2) acc2=a; else acc3=a;
    }
  }

  // ---- epilogue: bias + (jt>=8) slot interpolation; D: col=l&15, row=(l>>4)*4+r
  float bias[4];
  #pragma unroll
  for (int nf=0; nf<4; ++nf){
    int j = jt*64 + nf*16 + ar;
    bias[nf] = b_ih[2*H_ + j] + b_hh[2*H_ + j];
  }
  #pragma unroll
  for (int r=0; r<4; ++r){
    int b = b0 + mw + kb*4 + r;
    float dldv=0.f, dhdv=0.f, tldv=0.f, thdv=0.f;
    int dlv=0, dhv=0, tlv=0, thv=0;
    if (jt >= 8){
      int bt = b*T_ + t;
      dldv=d_ld[bt]; dhdv=d_hd[bt]; tldv=t_ld[bt]; thdv=t_hd[bt];
      dlv=d_l[bt]; dhv=d_h[bt]; tlv=t_l[bt]; thv=t_h[bt];
    }
    #pragma unroll
    for (int nf=0; nf<4; ++nf){
      int j = jt*64 + nf*16 + ar;
      float v = ((nf==0)?acc0[r]:(nf==1)?acc1[r]:(nf==2)?acc2[r]:acc3[r]) + bias[nf];
      if (jt >= 8){
        int jo = j - 512;
        v += dhdv*es_proj[dlv*H_+jo] + dldv*es_proj[dhv*H_+jo]
           + thdv*eq_proj[tlv*H_+jo] + tldv*eq_proj[thv*H_+jo];
      }
      P[((size_t)t*B_ + b)*1024 + j] = v;
    }
  }
}

// ---------------- phase 1 fallback (r11 fp32 VALU version, proven) -----------------
__global__ __launch_bounds__(256) void k_phase1_f32(
  const int* __restrict__ batch_l, const float* __restrict__ embed_l,
  const float* __restrict__ w_ih, const float* __restrict__ b_ih, const float* __restrict__ b_hh,
  const float* __restrict__ t_ld, const float* __restrict__ t_hd,
  const int* __restrict__ t_l, const int* __restrict__ t_h,
  const float* __restrict__ d_ld, const float* __restrict__ d_hd,
  const int* __restrict__ d_l, const int* __restrict__ d_h,
  const float* __restrict__ es_proj, const float* __restrict__ eq_proj,
  float* __restrict__ P)
{
  __shared__ float As[8][72];
  __shared__ float Bs[8][72];
  __shared__ int ridx[64];
  int mt = blockIdx.x, jt = blockIdx.y;       // 200 x 16
  int t = mt >> 1, b0 = (mt & 1)*64;
  int tid = threadIdx.x;
  if (tid < 64) ridx[tid] = batch_l[(b0+tid)*T_ + t];
  __syncthreads();
  int ty = tid >> 4, tx = tid & 15;
  int r_s = tid >> 2;
  int kk_s = (tid & 3)*2;
  const float* arow = embed_l + (size_t)ridx[r_s]*D_ + kk_s;
  const float* brow = w_ih + (size_t)(2*H_ + jt*64 + r_s)*D_ + kk_s;
  float acc[4][4] = {};
  for (int kc = 0; kc < 32; ++kc) {
    int k0 = kc*8;
    float2 av = *(const float2*)(arow + k0);
    float2 bv = *(const float2*)(brow + k0);
    __syncthreads();
    As[kk_s][r_s] = av.x; As[kk_s+1][r_s] = av.y;
    Bs[kk_s][r_s] = bv.x; Bs[kk_s+1][r_s] = bv.y;
    __syncthreads();
    #pragma unroll
    for (int kk=0;kk<8;++kk){
      float4 a4 = *(const float4*)&As[kk][ty*4];
      float4 b4 = *(const float4*)&Bs[kk][tx*4];
      float avv[4] = {a4.x,a4.y,a4.z,a4.w};
      float bvv[4] = {b4.x,b4.y,b4.z,b4.w};
      #pragma unroll
      for (int i=0;i<4;++i)
        #pragma unroll
        for (int j=0;j<4;++j) acc[i][j] = fmaf(avv[i], bvv[j], acc[i][j]);
    }
  }
  int j0 = jt*64 + tx*4;
  float bias[4];
  #pragma unroll
  for (int j=0;j<4;++j) bias[j] = b_ih[2*H_ + j0 + j] + b_hh[2*H_ + j0 + j];
  #pragma unroll
  for (int i=0;i<4;++i){
    int b = b0 + ty*4 + i;
    size_t m = (size_t)t*B_ + b;
    float add[4] = {0.f,0.f,0.f,0.f};
    if (jt >= 8) {
      int bt = b*T_ + t;
      float dld = d_ld[bt], dhd = d_hd[bt];
      float tld = t_ld[bt], thd = t_hd[bt];
      int dl = d_l[bt], dh = d_h[bt], tl = t_l[bt], th = t_h[bt];
      int jo = j0 - 512;
      #pragma unroll
      for (int j=0;j<4;++j)
        add[j] = dhd*es_proj[dl*H_+jo+j] + dld*es_proj[dh*H_+jo+j]
               + thd*eq_proj[tl*H_+jo+j] + tld*eq_proj[th*H_+jo+j];
    }
    float4 o4;
    o4.x = acc[i][0] + bias[0] + add[0];
    o4.y = acc[i][1] + bias[1] + add[1];
    o4.z = acc[i][2] + bias[2] + add[2];
    o4.w = acc[i][3] + bias[3] + add[3];
    *(float4*)&P[m*1024 + j0] = o4;
  }
}

// ---------------- recurrence: persistent, 256 WGs x 256 thr = 16 bg x 16 js ----------------
// r11-EXACT (697us proven): LDS weights, float4 h LDS tiles, u64 relaxed-atomic h
// exchange, per-WG flag stores on one 64B line/bg polled by 16 lanes.
__global__ __launch_bounds__(256,1) void k_rec(
  const float* __restrict__ w_hh, const float* __restrict__ P,
  float* __restrict__ h_buf, unsigned* __restrict__ flags)
{
  extern __shared__ float sm[];
  float* Wt = sm;                               // [512][66] k-major, r = 4rq+{g0,g1,o0,o1}
  float4* hta = (float4*)(sm + 512*66);         // [512]: h[k][b0..b3]
  float4* htb = hta + 512;                      // [512]: h[k][b4..b7]
  int bid = blockIdx.x;
  int bg = bid & 15, js = bid >> 4;
  int tid = threadIdx.x;
  const float* Wgo = w_hh + (size_t)2*H_*H_;    // rows [0,512)=g, [512,1024)=o
  for (int it=0; it<32; ++it){                  // stage 64x512 weights
    int e4 = (it*256 + tid)*4;
    int k = e4 & 511, r = e4 >> 9;
    int jh_loc = 2*(r>>2) + (r&1);
    int part = (r>>1)&1;
    int grow = part*H_ + js*32 + jh_loc;
    float4 v = *(const float4*)(Wgo + (size_t)grow*H_ + k);
    Wt[(k+0)*66 + r] = v.x; Wt[(k+1)*66 + r] = v.y;
    Wt[(k+2)*66 + r] = v.z; Wt[(k+3)*66 + r] = v.w;
  }
  int rq = tid >> 4, kq = tid & 15;
  int j0 = js*32 + 2*rq;
  const int gb0 = bg*8;
  unsigned* bgflags = flags + bg*16;            // 16 u32 in one 64B line

  float2 pg = {0.f,0.f}, po = {0.f,0.f};
  if (kq < 8){
    size_t prow = (size_t)(gb0 + kq)*1024;
    pg = *(const float2*)&P[prow + j0];
    po = *(const float2*)&P[prow + 512 + j0];
  }
  __syncthreads();                              // weights staged

  for (int t=0; t<T_; ++t){
    int par = t & 1;
    if (t > 0){
      if (tid < 16){                            // one coalesced 64B line read per poll
        unsigned* f = bgflags + tid;
        int guard = 0;
        while (__hip_atomic_load(f, __ATOMIC_RELAXED, __HIP_MEMORY_SCOPE_AGENT) < (unsigned)t){
          __builtin_amdgcn_s_sleep(4);
          if (++guard > (1<<22)) break;         // safety bail (never in normal operation)
        }
      }
      __syncthreads();
    }
    // ---- stage h: thread tid loads u64 pair (k=2tid, 2tid+1) for b=0..7
    const unsigned long long* hsrc =
      (const unsigned long long*)(h_buf + (size_t)par*(B_*H_) + (size_t)gb0*H_) + tid;
    F2U64 v[8];
    #pragma unroll
    for (int b=0;b<8;++b)
      v[b].u = __hip_atomic_load(&hsrc[b*(H_/2)], __ATOMIC_RELAXED, __HIP_MEMORY_SCOPE_AGENT);
    hta[2*tid]   = make_float4(v[0].f.x, v[1].f.x, v[2].f.x, v[3].f.x);
    hta[2*tid+1] = make_float4(v[0].f.y, v[1].f.y, v[2].f.y, v[3].f.y);
    htb[2*tid]   = make_float4(v[4].f.x, v[5].f.x, v[6].f.x, v[7].f.x);
    htb[2*tid+1] = make_float4(v[4].f.y, v[5].f.y, v[6].f.y, v[7].f.y);
    __syncthreads();

    // ---- compute: acc[r][b] = sum over k-slice (k = kk*16+kq) of w[r][k]*h[k][b]
    float acc[4][8] = {};
    #pragma unroll 4
    for (int kk=0; kk<32; ++kk){
      int k = kk*16 + kq;
      float2 wA = *(const float2*)&Wt[k*66 + 4*rq];
      float2 wB = *(const float2*)&Wt[k*66 + 4*rq + 2];
      float4 ha = hta[k];
      float4 hb = htb[k];
      float hvv[8] = {ha.x,ha.y,ha.z,ha.w,hb.x,hb.y,hb.z,hb.w};
      #pragma unroll
      for (int i=0;i<8;++i){
        acc[0][i] = fmaf(wA.x, hvv[i], acc[0][i]);
        acc[1][i] = fmaf(wA.y, hvv[i], acc[1][i]);
        acc[2][i] = fmaf(wB.x, hvv[i], acc[2][i]);
        acc[3][i] = fmaf(wB.y, hvv[i], acc[3][i]);
      }
    }
    // ---- butterfly reduce over the 16-lane kq groups
    #pragma unroll
    for (int r=0;r<4;++r)
      #pragma unroll
      for (int i=0;i<8;++i){
        float s = acc[r][i];
        s += __shfl_xor(s, 1, 64);
        s += __shfl_xor(s, 2, 64);
        s += __shfl_xor(s, 4, 64);
        s += __shfl_xor(s, 8, 64);
        acc[r][i] = s;
      }
    // ---- epilogue: lane kq=b (b<8) stores h(j0),h(j0+1) for batch b as one u64 atomic
    if (kq < 8){
      int b = kq;
      float gg0 = acc[0][b] + pg.x, gg1 = acc[1][b] + pg.y;
      float oo0 = acc[2][b] + po.x, oo1 = acc[3][b] + po.y;
      F2U64 h2;
      h2.f.x = sigm_(oo0)*tanh_(tanh_(gg0));
      h2.f.y = sigm_(oo1)*tanh_(tanh_(gg1));
      __hip_atomic_store((unsigned long long*)
        (h_buf + (size_t)(1-par)*(B_*H_) + (size_t)(gb0 + b)*H_ + j0),
        h2.u, __ATOMIC_RELAXED, __HIP_MEMORY_SCOPE_AGENT);
    }
    __syncthreads();   // per-wave vmcnt(0): h loads consumed AND h stores visible
    if (t+1 < T_){
      if (tid == 0)
        __hip_atomic_store(bgflags + js, (unsigned)(t+1),
                           __ATOMIC_RELAXED, __HIP_MEMORY_SCOPE_AGENT);
      if (kq < 8){   // prefetch next step's P; overlaps peers' completion
        size_t prow = ((size_t)(t+1)*B_ + gb0 + kq)*1024;
        pg = *(const float2*)&P[prow + j0];
        po = *(const float2*)&P[prow + 512 + j0];
      }
    }
  }
}

// ---------------- classifier: out = hT @ w_out.T + b_out ----------------
__global__ __launch_bounds__(256) void k_cls(
  const float* __restrict__ hT, const float* __restrict__ w_out,
  const float* __restrict__ b_out, float* __restrict__ out)
{
  __shared__ float wt[32*68];     // [k][l] k-major
  __shared__ float htl[32*132];   // [k][b]
  int l0 = blockIdx.x * 64;       // 625 blocks
  int tid = threadIdx.x;
  int lq = tid >> 4, bq = tid & 15;
  float acc[4][8] = {};
  for (int kc=0; kc<16; ++kc){
    int k0 = kc*32;
    __syncthreads();
    for (int it=0; it<8; ++it){
      int e = it*256 + tid; int k = e & 31, l = e >> 5;
      wt[k*68 + l] = w_out[(size_t)(l0+l)*H_ + k0 + k];
    }
    for (int it=0; it<16; ++it){
      int e = it*256 + tid; int k = e & 31, b = e >> 5;
      htl[k*132 + b] = hT[(size_t)b*H_ + k0 + k];
    }
    __syncthreads();
    #pragma unroll 4
    for (int k=0;k<32;++k){
      float4 w4 = *(const float4*)&wt[k*68 + lq*4];
      float4 h0 = *(const float4*)&htl[k*132 + bq*8];
      float4 h1 = *(const float4*)&htl[k*132 + bq*8 + 4];
      float wv[4] = {w4.x,w4.y,w4.z,w4.w};
      float hv[8] = {h0.x,h0.y,h0.z,h0.w,h1.x,h1.y,h1.z,h1.w};
      #pragma unroll
      for (int m=0;m<4;++m)
        #pragma unroll
        for (int i=0;i<8;++i) acc[m][i] = fmaf(wv[m], hv[i], acc[m][i]);
    }
  }
  int l = l0 + lq*4;
  float4 bo = *(const float4*)&b_out[l];
  #pragma unroll
  for (int i=0;i<8;++i){
    int b = bq*8 + i;
    float4 o4;
    o4.x = acc[0][i] + bo.x; o4.y = acc[1][i] + bo.y;
    o4.z = acc[2][i] + bo.z; o4.w = acc[3][i] + bo.w;
    *(float4*)&out[(size_t)b*L_ + l] = o4;
  }
}

extern "C" void kernel_launch(void* const* d_in, const int* in_sizes, int n_in,
                              void* d_out, int out_size, void* d_ws, size_t ws_size,
                              hipStream_t stream) {
  const int*   batch_l = (const int*)  d_in[0];
  const float* t_ld    = (const float*)d_in[1];
  const float* t_hd    = (const float*)d_in[2];
  const int*   t_l     = (const int*)  d_in[3];
  const int*   t_h     = (const int*)  d_in[4];
  const float* d_ld    = (const float*)d_in[5];
  const float* d_hd    = (const float*)d_in[6];
  const int*   d_l     = (const int*)  d_in[7];
  const int*   d_h     = (const int*)  d_in[8];
  const float* embed_l = (const float*)d_in[9];
  const float* embed_s = (const float*)d_in[10];
  const float* embed_q = (const float*)d_in[11];
  const float* w_ih    = (const float*)d_in[12];
  const float* w_hh    = (const float*)d_in[13];
  const float* w_s     = (const float*)d_in[14];
  const float* w_q     = (const float*)d_in[15];
  const float* b_ih    = (const float*)d_in[16];
  const float* b_hh    = (const float*)d_in[17];
  const float* w_out   = (const float*)d_in[18];
  const float* b_out   = (const float*)d_in[19];
  float* out = (float*)d_out;

  // workspace layout (float offsets)
  float* ws = (float*)d_ws;
  const size_t P_off   = 0;                         // 13107200 f
  const size_t h_off   = 13107200;                  // 131072 f (2*B*H double buffer)
  const size_t es_off  = h_off + 131072;            // 5120 f
  const size_t eq_off  = es_off + 5120;             // 5120 f
  const size_t flg_off = eq_off + 5120;             // 256 u32
  const size_t ehi_off = flg_off + 256;             // 40000*256 ushort = 5120000 f
  const size_t elo_off = ehi_off + 5120000;
  const size_t whi_off = elo_off + 5120000;         // 1024*256 ushort = 131072 f
  const size_t wlo_off = whi_off + 131072;
  const size_t need_base = (flg_off + 256)*4 + 64;
  const size_t need_full = (wlo_off + 131072)*4 + 64;
  if (ws_size < need_base) return;

  float* P        = ws + P_off;
  float* h_buf    = ws + h_off;
  float* es_proj  = ws + es_off;
  float* eq_proj  = ws + eq_off;
  unsigned* flags = (unsigned*)(ws + flg_off);
  unsigned short* Ehi = (unsigned short*)(ws + ehi_off);
  unsigned short* Elo = (unsigned short*)(ws + elo_off);
  unsigned short* Whi = (unsigned short*)(ws + whi_off);
  unsigned short* Wlo = (unsigned short*)(ws + wlo_off);

  hipFuncSetAttribute(reinterpret_cast<const void*>(k_rec),
                      hipFuncAttributeMaxDynamicSharedMemorySize, 151552);

  k_zero<<<513, 256, 0, stream>>>(h_buf, flags);
  k_prep<<<40, 256, 0, stream>>>(embed_s, embed_q, w_s, w_q, es_proj, eq_proj);
  if (ws_size >= need_full){
    k_conv<<<10256, 256, 0, stream>>>(embed_l, w_ih, Ehi, Elo, Whi, Wlo);
    k_phase1<<<dim3(200,16), 256, 0, stream>>>(batch_l, Ehi, Elo, Whi, Wlo,
        b_ih, b_hh, t_ld, t_hd, t_l, t_h, d_ld, d_hd, d_l, d_h, es_proj, eq_proj, P);
  } else {
    k_phase1_f32<<<dim3(200,16), 256, 0, stream>>>(batch_l, embed_l, w_ih, b_ih, b_hh,
        t_ld, t_hd, t_l, t_h, d_ld, d_hd, d_l, d_h, es_proj, eq_proj, P);
  }
  k_rec<<<256, 256, 151552, stream>>>(w_hh, P, h_buf, flags);
  k_cls<<<625, 256, 0, stream>>>(h_buf, w_out, b_out, out);
}

// Round 19
// 889.085 us; speedup vs baseline: 1.2021x; 1.0155x over previous
//
#include <hip/hip_runtime.h>

#define B_ 128
#define T_ 100
#define D_ 256
#define H_ 512
#define L_ 40000
#define S_ 10

__device__ __forceinline__ float sigm_(float x){ return 1.f/(1.f + __expf(-x)); }
__device__ __forceinline__ float tanh_(float x){ return 1.f - 2.f/(__expf(2.f*x) + 1.f); }

union F2U64 { float2 f; unsigned long long u; };

typedef __attribute__((ext_vector_type(8))) short bf16x8;
typedef __attribute__((ext_vector_type(4))) float f32x4;

// RNE fp32 -> bf16 (as ushort)
__device__ __forceinline__ unsigned short bfhi_(float x){
  unsigned u = __float_as_uint(x);
  return (unsigned short)((u + 0x7FFFu + ((u >> 16) & 1u)) >> 16);
}
__device__ __forceinline__ float bf2f_(unsigned short h){
  return __uint_as_float(((unsigned)h) << 16);
}

// ---------------- fused init: zero h double-buffer + flags + slot projections -------
__global__ void k_init(float* __restrict__ h_buf, unsigned* __restrict__ flags,
                       const float* __restrict__ embed_s, const float* __restrict__ embed_q,
                       const float* __restrict__ w_s, const float* __restrict__ w_q,
                       float* __restrict__ es_proj, float* __restrict__ eq_proj){
  int bid = blockIdx.x, tid = threadIdx.x;
  if (bid < 512){ h_buf[bid*256 + tid] = 0.f; return; }          // 2*B*H floats
  if (bid == 512){ if (tid < 256) flags[tid] = 0u; return; }     // 256 u32
  int b2 = bid - 513;                                            // 0..39: projections
  int table = b2/20, rem = b2%20, s = rem/2, half = rem%2;
  int jo = half*256 + tid;
  const float* emb = (table ? embed_q : embed_s) + s*D_;
  const float* w   = (table ? w_q : w_s) + (size_t)(2*H_ + jo)*D_;   // o-gate rows
  float acc = 0.f;
  #pragma unroll 4
  for (int k=0;k<D_;++k) acc = fmaf(emb[k], w[k], acc);
  (table ? eq_proj : es_proj)[s*H_ + jo] = acc;
}

// ---------------- one-time bf16 hi/lo conversion of w_ih g/o rows (1024 x 256) ------
__global__ __launch_bounds__(256) void k_conv_w(
  const float* __restrict__ w_ih,
  unsigned short* __restrict__ Whi, unsigned short* __restrict__ Wlo)
{
  int g = blockIdx.x*256 + threadIdx.x;      // float4 group, 0..65535
  size_t row = (size_t)(g >> 6), k4 = (size_t)(g & 63)*4;
  const float* src = w_ih + (2*H_ + row)*D_ + k4;
  size_t off = row*D_ + k4;
  float4 v = *(const float4*)src;
  ushort4 hi, lo;
  hi.x = bfhi_(v.x); lo.x = bfhi_(v.x - bf2f_(hi.x));
  hi.y = bfhi_(v.y); lo.y = bfhi_(v.y - bf2f_(hi.y));
  hi.z = bfhi_(v.z); lo.z = bfhi_(v.z - bf2f_(hi.z));
  hi.w = bfhi_(v.w); lo.w = bfhi_(v.w - bf2f_(hi.w));
  *(ushort4*)(Whi + off) = hi;
  *(ushort4*)(Wlo + off) = lo;
}

// ---------------- phase 1 (MFMA, split-bf16; A converted in registers) --------------
// Same verified math/mapping as r17/r18 (absmax 4.88e-4). A rows load as fp32 float4
// directly from embed_l (L3-cached across jt blocks) and convert to bf16 hi/lo in
// registers -- no 82MB embed conversion round-trip. B from pre-converted Whi/Wlo.
__global__ __launch_bounds__(256) void k_phase1(
  const int* __restrict__ batch_l, const float* __restrict__ embed_l,
  const unsigned short* __restrict__ Whi, const unsigned short* __restrict__ Wlo,
  const float* __restrict__ b_ih, const float* __restrict__ b_hh,
  const float* __restrict__ t_ld, const float* __restrict__ t_hd,
  const int* __restrict__ t_l, const int* __restrict__ t_h,
  const float* __restrict__ d_ld, const float* __restrict__ d_hd,
  const int* __restrict__ d_l, const int* __restrict__ d_h,
  const float* __restrict__ es_proj, const float* __restrict__ eq_proj,
  float* __restrict__ P)
{
  __shared__ int ridx[64];
  int mt = blockIdx.x, jt = blockIdx.y;                  // 200 x 16
  int t = mt >> 1, b0 = (mt & 1)*64;
  int tid = threadIdx.x;
  if (tid < 64) ridx[tid] = batch_l[(b0+tid)*T_ + t];
  __syncthreads();

  int lane = tid & 63, wv = tid >> 6;
  int ar = lane & 15, kb = lane >> 4;
  int mw = wv*16;
  f32x4 acc0 = {0.f,0.f,0.f,0.f}, acc1 = {0.f,0.f,0.f,0.f};
  f32x4 acc2 = {0.f,0.f,0.f,0.f}, acc3 = {0.f,0.f,0.f,0.f};
  const float* arow_f = embed_l + (size_t)ridx[mw + ar]*D_ + kb*8;
  const size_t brow0 = (size_t)(jt*64 + ar)*D_ + kb*8;   // nf adds 16*D_
  #pragma unroll
  for (int kc=0; kc<8; ++kc){
    float4 f0 = *(const float4*)(arow_f + kc*32);
    float4 f1 = *(const float4*)(arow_f + kc*32 + 4);
    float vv[8] = {f0.x,f0.y,f0.z,f0.w,f1.x,f1.y,f1.z,f1.w};
    bf16x8 a_hi, a_lo;
    #pragma unroll
    for (int i=0;i<8;++i){
      unsigned short h = bfhi_(vv[i]);
      a_hi[i] = (short)h;
      a_lo[i] = (short)bfhi_(vv[i] - bf2f_(h));
    }
    #pragma unroll
    for (int nf=0; nf<4; ++nf){
      bf16x8 b_hi = *(const bf16x8*)(Whi + brow0 + (size_t)nf*16*D_ + kc*32);
      bf16x8 b_lo = *(const bf16x8*)(Wlo + brow0 + (size_t)nf*16*D_ + kc*32);
      f32x4 a = (nf==0)?acc0:(nf==1)?acc1:(nf==2)?acc2:acc3;
      a = __builtin_amdgcn_mfma_f32_16x16x32_bf16(a_hi, b_hi, a, 0, 0, 0);
      a = __builtin_amdgcn_mfma_f32_16x16x32_bf16(a_hi, b_lo, a, 0, 0, 0);
      a = __builtin_amdgcn_mfma_f32_16x16x32_bf16(a_lo, b_hi, a, 0, 0, 0);
      if (nf==0) acc0=a; else if (nf==1) acc1=a; else if (nf==2) acc2=a; else acc3=a;
    }
  }

  // ---- epilogue: bias + (jt>=8) slot interpolation; D: col=l&15, row=(l>>4)*4+r
  float bias[4];
  #pragma unroll
  for (int nf=0; nf<4; ++nf){
    int j = jt*64 + nf*16 + ar;
    bias[nf] = b_ih[2*H_ + j] + b_hh[2*H_ + j];
  }
  #pragma unroll
  for (int r=0; r<4; ++r){
    int b = b0 + mw + kb*4 + r;
    float dldv=0.f, dhdv=0.f, tldv=0.f, thdv=0.f;
    int dlv=0, dhv=0, tlv=0, thv=0;
    if (jt >= 8){
      int bt = b*T_ + t;
      dldv=d_ld[bt]; dhdv=d_hd[bt]; tldv=t_ld[bt]; thdv=t_hd[bt];
      dlv=d_l[bt]; dhv=d_h[bt]; tlv=t_l[bt]; thv=t_h[bt];
    }
    #pragma unroll
    for (int nf=0; nf<4; ++nf){
      int j = jt*64 + nf*16 + ar;
      float v = ((nf==0)?acc0[r]:(nf==1)?acc1[r]:(nf==2)?acc2[r]:acc3[r]) + bias[nf];
      if (jt >= 8){
        int jo = j - 512;
        v += dhdv*es_proj[dlv*H_+jo] + dldv*es_proj[dhv*H_+jo]
           + thdv*eq_proj[tlv*H_+jo] + tldv*eq_proj[thv*H_+jo];
      }
      P[((size_t)t*B_ + b)*1024 + j] = v;
    }
  }
}

// ---------------- phase 1 fallback (r11 fp32 VALU version, proven) -----------------
__global__ __launch_bounds__(256) void k_phase1_f32(
  const int* __restrict__ batch_l, const float* __restrict__ embed_l,
  const float* __restrict__ w_ih, const float* __restrict__ b_ih, const float* __restrict__ b_hh,
  const float* __restrict__ t_ld, const float* __restrict__ t_hd,
  const int* __restrict__ t_l, const int* __restrict__ t_h,
  const float* __restrict__ d_ld, const float* __restrict__ d_hd,
  const int* __restrict__ d_l, const int* __restrict__ d_h,
  const float* __restrict__ es_proj, const float* __restrict__ eq_proj,
  float* __restrict__ P)
{
  __shared__ float As[8][72];
  __shared__ float Bs[8][72];
  __shared__ int ridx[64];
  int mt = blockIdx.x, jt = blockIdx.y;       // 200 x 16
  int t = mt >> 1, b0 = (mt & 1)*64;
  int tid = threadIdx.x;
  if (tid < 64) ridx[tid] = batch_l[(b0+tid)*T_ + t];
  __syncthreads();
  int ty = tid >> 4, tx = tid & 15;
  int r_s = tid >> 2;
  int kk_s = (tid & 3)*2;
  const float* arow = embed_l + (size_t)ridx[r_s]*D_ + kk_s;
  const float* brow = w_ih + (size_t)(2*H_ + jt*64 + r_s)*D_ + kk_s;
  float acc[4][4] = {};
  for (int kc = 0; kc < 32; ++kc) {
    int k0 = kc*8;
    float2 av = *(const float2*)(arow + k0);
    float2 bv = *(const float2*)(brow + k0);
    __syncthreads();
    As[kk_s][r_s] = av.x; As[kk_s+1][r_s] = av.y;
    Bs[kk_s][r_s] = bv.x; Bs[kk_s+1][r_s] = bv.y;
    __syncthreads();
    #pragma unroll
    for (int kk=0;kk<8;++kk){
      float4 a4 = *(const float4*)&As[kk][ty*4];
      float4 b4 = *(const float4*)&Bs[kk][tx*4];
      float avv[4] = {a4.x,a4.y,a4.z,a4.w};
      float bvv[4] = {b4.x,b4.y,b4.z,b4.w};
      #pragma unroll
      for (int i=0;i<4;++i)
        #pragma unroll
        for (int j=0;j<4;++j) acc[i][j] = fmaf(avv[i], bvv[j], acc[i][j]);
    }
  }
  int j0 = jt*64 + tx*4;
  float bias[4];
  #pragma unroll
  for (int j=0;j<4;++j) bias[j] = b_ih[2*H_ + j0 + j] + b_hh[2*H_ + j0 + j];
  #pragma unroll
  for (int i=0;i<4;++i){
    int b = b0 + ty*4 + i;
    size_t m = (size_t)t*B_ + b;
    float add[4] = {0.f,0.f,0.f,0.f};
    if (jt >= 8) {
      int bt = b*T_ + t;
      float dld = d_ld[bt], dhd = d_hd[bt];
      float tld = t_ld[bt], thd = t_hd[bt];
      int dl = d_l[bt], dh = d_h[bt], tl = t_l[bt], th = t_h[bt];
      int jo = j0 - 512;
      #pragma unroll
      for (int j=0;j<4;++j)
        add[j] = dhd*es_proj[dl*H_+jo+j] + dld*es_proj[dh*H_+jo+j]
               + thd*eq_proj[tl*H_+jo+j] + tld*eq_proj[th*H_+jo+j];
    }
    float4 o4;
    o4.x = acc[i][0] + bias[0] + add[0];
    o4.y = acc[i][1] + bias[1] + add[1];
    o4.z = acc[i][2] + bias[2] + add[2];
    o4.w = acc[i][3] + bias[3] + add[3];
    *(float4*)&P[m*1024 + j0] = o4;
  }
}

// ---------------- recurrence: persistent, 256 WGs x 256 thr = 16 bg x 16 js ----------------
// r11-EXACT (697us proven): LDS weights, float4 h LDS tiles, u64 relaxed-atomic h
// exchange, per-WG flag stores on one 64B line/bg polled by 16 lanes.
__global__ __launch_bounds__(256,1) void k_rec(
  const float* __restrict__ w_hh, const float* __restrict__ P,
  float* __restrict__ h_buf, unsigned* __restrict__ flags)
{
  extern __shared__ float sm[];
  float* Wt = sm;                               // [512][66] k-major, r = 4rq+{g0,g1,o0,o1}
  float4* hta = (float4*)(sm + 512*66);         // [512]: h[k][b0..b3]
  float4* htb = hta + 512;                      // [512]: h[k][b4..b7]
  int bid = blockIdx.x;
  int bg = bid & 15, js = bid >> 4;
  int tid = threadIdx.x;
  const float* Wgo = w_hh + (size_t)2*H_*H_;    // rows [0,512)=g, [512,1024)=o
  for (int it=0; it<32; ++it){                  // stage 64x512 weights
    int e4 = (it*256 + tid)*4;
    int k = e4 & 511, r = e4 >> 9;
    int jh_loc = 2*(r>>2) + (r&1);
    int part = (r>>1)&1;
    int grow = part*H_ + js*32 + jh_loc;
    float4 v = *(const float4*)(Wgo + (size_t)grow*H_ + k);
    Wt[(k+0)*66 + r] = v.x; Wt[(k+1)*66 + r] = v.y;
    Wt[(k+2)*66 + r] = v.z; Wt[(k+3)*66 + r] = v.w;
  }
  int rq = tid >> 4, kq = tid & 15;
  int j0 = js*32 + 2*rq;
  const int gb0 = bg*8;
  unsigned* bgflags = flags + bg*16;            // 16 u32 in one 64B line

  float2 pg = {0.f,0.f}, po = {0.f,0.f};
  if (kq < 8){
    size_t prow = (size_t)(gb0 + kq)*1024;
    pg = *(const float2*)&P[prow + j0];
    po = *(const float2*)&P[prow + 512 + j0];
  }
  __syncthreads();                              // weights staged

  for (int t=0; t<T_; ++t){
    int par = t & 1;
    if (t > 0){
      if (tid < 16){                            // one coalesced 64B line read per poll
        unsigned* f = bgflags + tid;
        int guard = 0;
        while (__hip_atomic_load(f, __ATOMIC_RELAXED, __HIP_MEMORY_SCOPE_AGENT) < (unsigned)t){
          __builtin_amdgcn_s_sleep(4);
          if (++guard > (1<<22)) break;         // safety bail (never in normal operation)
        }
      }
      __syncthreads();
    }
    // ---- stage h: thread tid loads u64 pair (k=2tid, 2tid+1) for b=0..7
    const unsigned long long* hsrc =
      (const unsigned long long*)(h_buf + (size_t)par*(B_*H_) + (size_t)gb0*H_) + tid;
    F2U64 v[8];
    #pragma unroll
    for (int b=0;b<8;++b)
      v[b].u = __hip_atomic_load(&hsrc[b*(H_/2)], __ATOMIC_RELAXED, __HIP_MEMORY_SCOPE_AGENT);
    hta[2*tid]   = make_float4(v[0].f.x, v[1].f.x, v[2].f.x, v[3].f.x);
    hta[2*tid+1] = make_float4(v[0].f.y, v[1].f.y, v[2].f.y, v[3].f.y);
    htb[2*tid]   = make_float4(v[4].f.x, v[5].f.x, v[6].f.x, v[7].f.x);
    htb[2*tid+1] = make_float4(v[4].f.y, v[5].f.y, v[6].f.y, v[7].f.y);
    __syncthreads();

    // ---- compute: acc[r][b] = sum over k-slice (k = kk*16+kq) of w[r][k]*h[k][b]
    float acc[4][8] = {};
    #pragma unroll 4
    for (int kk=0; kk<32; ++kk){
      int k = kk*16 + kq;
      float2 wA = *(const float2*)&Wt[k*66 + 4*rq];
      float2 wB = *(const float2*)&Wt[k*66 + 4*rq + 2];
      float4 ha = hta[k];
      float4 hb = htb[k];
      float hvv[8] = {ha.x,ha.y,ha.z,ha.w,hb.x,hb.y,hb.z,hb.w};
      #pragma unroll
      for (int i=0;i<8;++i){
        acc[0][i] = fmaf(wA.x, hvv[i], acc[0][i]);
        acc[1][i] = fmaf(wA.y, hvv[i], acc[1][i]);
        acc[2][i] = fmaf(wB.x, hvv[i], acc[2][i]);
        acc[3][i] = fmaf(wB.y, hvv[i], acc[3][i]);
      }
    }
    // ---- butterfly reduce over the 16-lane kq groups
    #pragma unroll
    for (int r=0;r<4;++r)
      #pragma unroll
      for (int i=0;i<8;++i){
        float s = acc[r][i];
        s += __shfl_xor(s, 1, 64);
        s += __shfl_xor(s, 2, 64);
        s += __shfl_xor(s, 4, 64);
        s += __shfl_xor(s, 8, 64);
        acc[r][i] = s;
      }
    // ---- epilogue: lane kq=b (b<8) stores h(j0),h(j0+1) for batch b as one u64 atomic
    if (kq < 8){
      int b = kq;
      float gg0 = acc[0][b] + pg.x, gg1 = acc[1][b] + pg.y;
      float oo0 = acc[2][b] + po.x, oo1 = acc[3][b] + po.y;
      F2U64 h2;
      h2.f.x = sigm_(oo0)*tanh_(tanh_(gg0));
      h2.f.y = sigm_(oo1)*tanh_(tanh_(gg1));
      __hip_atomic_store((unsigned long long*)
        (h_buf + (size_t)(1-par)*(B_*H_) + (size_t)(gb0 + b)*H_ + j0),
        h2.u, __ATOMIC_RELAXED, __HIP_MEMORY_SCOPE_AGENT);
    }
    __syncthreads();   // per-wave vmcnt(0): h loads consumed AND h stores visible
    if (t+1 < T_){
      if (tid == 0)
        __hip_atomic_store(bgflags + js, (unsigned)(t+1),
                           __ATOMIC_RELAXED, __HIP_MEMORY_SCOPE_AGENT);
      if (kq < 8){   // prefetch next step's P; overlaps peers' completion
        size_t prow = ((size_t)(t+1)*B_ + gb0 + kq)*1024;
        pg = *(const float2*)&P[prow + j0];
        po = *(const float2*)&P[prow + 512 + j0];
      }
    }
  }
}

// ---------------- classifier: out = hT @ w_out.T + b_out (float4 staging) ----------
__global__ __launch_bounds__(256) void k_cls(
  const float* __restrict__ hT, const float* __restrict__ w_out,
  const float* __restrict__ b_out, float* __restrict__ out)
{
  __shared__ float wt[32*68];     // [k][l] k-major
  __shared__ float htl[32*132];   // [k][b]
  int l0 = blockIdx.x * 64;       // 625 blocks
  int tid = threadIdx.x;
  int lq = tid >> 4, bq = tid & 15;
  float acc[4][8] = {};
  for (int kc=0; kc<16; ++kc){
    int k0 = kc*32;
    __syncthreads();
    #pragma unroll
    for (int it=0; it<2; ++it){   // w_out tile: 64 l x 32 k via float4
      int f = it*256 + tid;       // 0..511
      int l = f >> 3, k4 = (f & 7)*4;
      float4 v = *(const float4*)&w_out[(size_t)(l0+l)*H_ + k0 + k4];
      wt[(k4+0)*68 + l] = v.x; wt[(k4+1)*68 + l] = v.y;
      wt[(k4+2)*68 + l] = v.z; wt[(k4+3)*68 + l] = v.w;
    }
    #pragma unroll
    for (int it=0; it<4; ++it){   // hT tile: 128 b x 32 k via float4
      int f = it*256 + tid;       // 0..1023
      int b = f >> 3, k4 = (f & 7)*4;
      float4 v = *(const float4*)&hT[(size_t)b*H_ + k0 + k4];
      htl[(k4+0)*132 + b] = v.x; htl[(k4+1)*132 + b] = v.y;
      htl[(k4+2)*132 + b] = v.z; htl[(k4+3)*132 + b] = v.w;
    }
    __syncthreads();
    #pragma unroll 4
    for (int k=0;k<32;++k){
      float4 w4 = *(const float4*)&wt[k*68 + lq*4];
      float4 h0 = *(const float4*)&htl[k*132 + bq*8];
      float4 h1 = *(const float4*)&htl[k*132 + bq*8 + 4];
      float wv[4] = {w4.x,w4.y,w4.z,w4.w};
      float hv[8] = {h0.x,h0.y,h0.z,h0.w,h1.x,h1.y,h1.z,h1.w};
      #pragma unroll
      for (int m=0;m<4;++m)
        #pragma unroll
        for (int i=0;i<8;++i) acc[m][i] = fmaf(wv[m], hv[i], acc[m][i]);
    }
  }
  int l = l0 + lq*4;
  float4 bo = *(const float4*)&b_out[l];
  #pragma unroll
  for (int i=0;i<8;++i){
    int b = bq*8 + i;
    float4 o4;
    o4.x = acc[0][i] + bo.x; o4.y = acc[1][i] + bo.y;
    o4.z = acc[2][i] + bo.z; o4.w = acc[3][i] + bo.w;
    *(float4*)&out[(size_t)b*L_ + l] = o4;
  }
}

extern "C" void kernel_launch(void* const* d_in, const int* in_sizes, int n_in,
                              void* d_out, int out_size, void* d_ws, size_t ws_size,
                              hipStream_t stream) {
  const int*   batch_l = (const int*)  d_in[0];
  const float* t_ld    = (const float*)d_in[1];
  const float* t_hd    = (const float*)d_in[2];
  const int*   t_l     = (const int*)  d_in[3];
  const int*   t_h     = (const int*)  d_in[4];
  const float* d_ld    = (const float*)d_in[5];
  const float* d_hd    = (const float*)d_in[6];
  const int*   d_l     = (const int*)  d_in[7];
  const int*   d_h     = (const int*)  d_in[8];
  const float* embed_l = (const float*)d_in[9];
  const float* embed_s = (const float*)d_in[10];
  const float* embed_q = (const float*)d_in[11];
  const float* w_ih    = (const float*)d_in[12];
  const float* w_hh    = (const float*)d_in[13];
  const float* w_s     = (const float*)d_in[14];
  const float* w_q     = (const float*)d_in[15];
  const float* b_ih    = (const float*)d_in[16];
  const float* b_hh    = (const float*)d_in[17];
  const float* w_out   = (const float*)d_in[18];
  const float* b_out   = (const float*)d_in[19];
  float* out = (float*)d_out;

  // workspace layout (float offsets)
  float* ws = (float*)d_ws;
  const size_t P_off   = 0;                         // 13107200 f
  const size_t h_off   = 13107200;                  // 131072 f (2*B*H double buffer)
  const size_t es_off  = h_off + 131072;            // 5120 f
  const size_t eq_off  = es_off + 5120;             // 5120 f
  const size_t flg_off = eq_off + 5120;             // 256 u32
  const size_t whi_off = flg_off + 256;             // 1024*256 ushort = 131072 f
  const size_t wlo_off = whi_off + 131072;
  const size_t need_base = (flg_off + 256)*4 + 64;
  const size_t need_full = (wlo_off + 131072)*4 + 64;
  if (ws_size < need_base) return;

  float* P        = ws + P_off;
  float* h_buf    = ws + h_off;
  float* es_proj  = ws + es_off;
  float* eq_proj  = ws + eq_off;
  unsigned* flags = (unsigned*)(ws + flg_off);
  unsigned short* Whi = (unsigned short*)(ws + whi_off);
  unsigned short* Wlo = (unsigned short*)(ws + wlo_off);

  hipFuncSetAttribute(reinterpret_cast<const void*>(k_rec),
                      hipFuncAttributeMaxDynamicSharedMemorySize, 151552);

  k_init<<<553, 256, 0, stream>>>(h_buf, flags, embed_s, embed_q, w_s, w_q,
                                  es_proj, eq_proj);
  if (ws_size >= need_full){
    k_conv_w<<<256, 256, 0, stream>>>(w_ih, Whi, Wlo);
    k_phase1<<<dim3(200,16), 256, 0, stream>>>(batch_l, embed_l, Whi, Wlo,
        b_ih, b_hh, t_ld, t_hd, t_l, t_h, d_ld, d_hd, d_l, d_h, es_proj, eq_proj, P);
  } else {
    k_phase1_f32<<<dim3(200,16), 256, 0, stream>>>(batch_l, embed_l, w_ih, b_ih, b_hh,
        t_ld, t_hd, t_l, t_h, d_ld, d_hd, d_l, d_h, es_proj, eq_proj, P);
  }
  k_rec<<<256, 256, 151552, stream>>>(w_hh, P, h_buf, flags);
  k_cls<<<625, 256, 0, stream>>>(h_buf, w_out, b_out, out);
}

// Round 20
// 558.853 us; speedup vs baseline: 1.9125x; 1.5909x over previous
//
#include <hip/hip_runtime.h>

#define B_ 128
#define T_ 100
#define D_ 256
#define H_ 512
#define L_ 40000
#define S_ 10

__device__ __forceinline__ float sigm_(float x){ return 1.f/(1.f + __expf(-x)); }
__device__ __forceinline__ float tanh_(float x){ return 1.f - 2.f/(__expf(2.f*x) + 1.f); }

typedef __attribute__((ext_vector_type(8))) short bf16x8;
typedef __attribute__((ext_vector_type(4))) float f32x4;

// RNE fp32 -> bf16 (as ushort)
__device__ __forceinline__ unsigned short bfhi_(float x){
  unsigned u = __float_as_uint(x);
  return (unsigned short)((u + 0x7FFFu + ((u >> 16) & 1u)) >> 16);
}
__device__ __forceinline__ float bf2f_(unsigned short h){
  return __uint_as_float(((unsigned)h) << 16);
}
// decode packed (hi | lo<<16) u32 -> fp32
__device__ __forceinline__ float decp_(unsigned u){
  return bf2f_((unsigned short)(u & 0xFFFFu)) + bf2f_((unsigned short)(u >> 16));
}

// ---------------- fused init: zero h_enc + flags + slot projections ----------------
__global__ void k_init(unsigned long long* __restrict__ h_enc, unsigned* __restrict__ flags,
                       const float* __restrict__ embed_s, const float* __restrict__ embed_q,
                       const float* __restrict__ w_s, const float* __restrict__ w_q,
                       float* __restrict__ es_proj, float* __restrict__ eq_proj){
  int bid = blockIdx.x, tid = threadIdx.x;
  if (bid < 256){ h_enc[bid*256 + tid] = 0ull; return; }         // 65536 u64 = 2*B*H/2
  if (bid == 256){ if (tid < 256) flags[tid] = 0u; return; }     // 256 u32
  int b2 = bid - 257;                                            // 0..39: projections
  int table = b2/20, rem = b2%20, s = rem/2, half = rem%2;
  int jo = half*256 + tid;
  const float* emb = (table ? embed_q : embed_s) + s*D_;
  const float* w   = (table ? w_q : w_s) + (size_t)(2*H_ + jo)*D_;   // o-gate rows
  float acc = 0.f;
  #pragma unroll 4
  for (int k=0;k<D_;++k) acc = fmaf(emb[k], w[k], acc);
  (table ? eq_proj : es_proj)[s*H_ + jo] = acc;
}

// ---------------- one-time bf16 hi/lo conversion of w_ih g/o rows (1024 x 256) ------
__global__ __launch_bounds__(256) void k_conv_w(
  const float* __restrict__ w_ih,
  unsigned short* __restrict__ Whi, unsigned short* __restrict__ Wlo)
{
  int g = blockIdx.x*256 + threadIdx.x;      // float4 group, 0..65535
  size_t row = (size_t)(g >> 6), k4 = (size_t)(g & 63)*4;
  const float* src = w_ih + (2*H_ + row)*D_ + k4;
  size_t off = row*D_ + k4;
  float4 v = *(const float4*)src;
  ushort4 hi, lo;
  hi.x = bfhi_(v.x); lo.x = bfhi_(v.x - bf2f_(hi.x));
  hi.y = bfhi_(v.y); lo.y = bfhi_(v.y - bf2f_(hi.y));
  hi.z = bfhi_(v.z); lo.z = bfhi_(v.z - bf2f_(hi.z));
  hi.w = bfhi_(v.w); lo.w = bfhi_(v.w - bf2f_(hi.w));
  *(ushort4*)(Whi + off) = hi;
  *(ushort4*)(Wlo + off) = lo;
}

// ---------------- phase 1 (MFMA, split-bf16; A converted in registers) --------------
// r19-identical (verified absmax 4.88e-4).
__global__ __launch_bounds__(256) void k_phase1(
  const int* __restrict__ batch_l, const float* __restrict__ embed_l,
  const unsigned short* __restrict__ Whi, const unsigned short* __restrict__ Wlo,
  const float* __restrict__ b_ih, const float* __restrict__ b_hh,
  const float* __restrict__ t_ld, const float* __restrict__ t_hd,
  const int* __restrict__ t_l, const int* __restrict__ t_h,
  const float* __restrict__ d_ld, const float* __restrict__ d_hd,
  const int* __restrict__ d_l, const int* __restrict__ d_h,
  const float* __restrict__ es_proj, const float* __restrict__ eq_proj,
  float* __restrict__ P)
{
  __shared__ int ridx[64];
  int mt = blockIdx.x, jt = blockIdx.y;                  // 200 x 16
  int t = mt >> 1, b0 = (mt & 1)*64;
  int tid = threadIdx.x;
  if (tid < 64) ridx[tid] = batch_l[(b0+tid)*T_ + t];
  __syncthreads();

  int lane = tid & 63, wv = tid >> 6;
  int ar = lane & 15, kb = lane >> 4;
  int mw = wv*16;
  f32x4 acc0 = {0.f,0.f,0.f,0.f}, acc1 = {0.f,0.f,0.f,0.f};
  f32x4 acc2 = {0.f,0.f,0.f,0.f}, acc3 = {0.f,0.f,0.f,0.f};
  const float* arow_f = embed_l + (size_t)ridx[mw + ar]*D_ + kb*8;
  const size_t brow0 = (size_t)(jt*64 + ar)*D_ + kb*8;   // nf adds 16*D_
  #pragma unroll
  for (int kc=0; kc<8; ++kc){
    float4 f0 = *(const float4*)(arow_f + kc*32);
    float4 f1 = *(const float4*)(arow_f + kc*32 + 4);
    float vv[8] = {f0.x,f0.y,f0.z,f0.w,f1.x,f1.y,f1.z,f1.w};
    bf16x8 a_hi, a_lo;
    #pragma unroll
    for (int i=0;i<8;++i){
      unsigned short h = bfhi_(vv[i]);
      a_hi[i] = (short)h;
      a_lo[i] = (short)bfhi_(vv[i] - bf2f_(h));
    }
    #pragma unroll
    for (int nf=0; nf<4; ++nf){
      bf16x8 b_hi = *(const bf16x8*)(Whi + brow0 + (size_t)nf*16*D_ + kc*32);
      bf16x8 b_lo = *(const bf16x8*)(Wlo + brow0 + (size_t)nf*16*D_ + kc*32);
      f32x4 a = (nf==0)?acc0:(nf==1)?acc1:(nf==2)?acc2:acc3;
      a = __builtin_amdgcn_mfma_f32_16x16x32_bf16(a_hi, b_hi, a, 0, 0, 0);
      a = __builtin_amdgcn_mfma_f32_16x16x32_bf16(a_hi, b_lo, a, 0, 0, 0);
      a = __builtin_amdgcn_mfma_f32_16x16x32_bf16(a_lo, b_hi, a, 0, 0, 0);
      if (nf==0) acc0=a; else if (nf==1) acc1=a; else if (nf==2) acc2=a; else acc3=a;
    }
  }

  float bias[4];
  #pragma unroll
  for (int nf=0; nf<4; ++nf){
    int j = jt*64 + nf*16 + ar;
    bias[nf] = b_ih[2*H_ + j] + b_hh[2*H_ + j];
  }
  #pragma unroll
  for (int r=0; r<4; ++r){
    int b = b0 + mw + kb*4 + r;
    float dldv=0.f, dhdv=0.f, tldv=0.f, thdv=0.f;
    int dlv=0, dhv=0, tlv=0, thv=0;
    if (jt >= 8){
      int bt = b*T_ + t;
      dldv=d_ld[bt]; dhdv=d_hd[bt]; tldv=t_ld[bt]; thdv=t_hd[bt];
      dlv=d_l[bt]; dhv=d_h[bt]; tlv=t_l[bt]; thv=t_h[bt];
    }
    #pragma unroll
    for (int nf=0; nf<4; ++nf){
      int j = jt*64 + nf*16 + ar;
      float v = ((nf==0)?acc0[r]:(nf==1)?acc1[r]:(nf==2)?acc2[r]:acc3[r]) + bias[nf];
      if (jt >= 8){
        int jo = j - 512;
        v += dhdv*es_proj[dlv*H_+jo] + dldv*es_proj[dhv*H_+jo]
           + thdv*eq_proj[tlv*H_+jo] + tldv*eq_proj[thv*H_+jo];
      }
      P[((size_t)t*B_ + b)*1024 + j] = v;
    }
  }
}

// ---------------- recurrence: persistent, 256 WGs x 256 thr = 16 bg x 16 js ---------
// Round-20: MFMA recurrence step. Per WG: out[32j g+o][8b] = W[64][512] x h[512][8b].
// Wave wv owns 16 A-rows = [g(js*32+wv*8+0..7), o(same j's)] -> one 16x16x32 M-frag;
// gg/oo for the same j land in lane L and L+32 -> one shfl_xor(32) pairs them (the old
// 160-instr butterfly is gone). Split-bf16 3-product MFMA (r17-verified, err ~2^-17).
// h exchange: u64 = [hi(j0),lo(j0),hi(j1),lo(j1)] bf16 -- same 8B, same r11 flag
// protocol (16 flags/bg on one 64B line; flag set after post-store barrier's vmcnt(0)
// drain; poll by tid<16). Consumer unpack is free: u64 low32/high32 are already the
// (hi|lo<<16) words stored per-k in LDS. W staged once as bf16 hi/lo (132KB LDS).
// B-frag: lane reads hb[k][col&7] u32 -> bh[e]=low16, bl[e]=high16 (dead cols 8..15
// only affect discarded D columns). D mapping (verified m89): col=l&15, row=(l>>4)*4+r.
__global__ __launch_bounds__(256,1) void k_rec(
  const float* __restrict__ w_hh, const float* __restrict__ P,
  unsigned long long* __restrict__ h_enc, unsigned* __restrict__ flags)
{
  extern __shared__ char smc[];
  unsigned short* Whi = (unsigned short*)smc;            // [64][528] bf16
  unsigned short* Wlo = Whi + 64*528;                    // [64][528]
  unsigned* hb = (unsigned*)(Wlo + 64*528);              // [512][10] (hi|lo<<16)
  int bid = blockIdx.x;
  int bg = bid & 15, js = bid >> 4;
  int tid = threadIdx.x;
  int lane = tid & 63, wv = tid >> 6;
  const int gb0 = bg*8;
  unsigned* bgflags = flags + bg*16;

  // ---- stage W once: LDS row r = w*16+rr; rr<8 -> g(js*32+w*8+rr), rr>=8 -> o(...)
  {
    int r = tid >> 2;                  // 0..63
    int c0 = (tid & 3)*128;
    int rr = r & 15;
    int jrow = js*32 + (r>>4)*8 + (rr & 7);
    const float* src = w_hh + (size_t)(((rr<8)?2:3)*H_ + jrow)*H_ + c0;
    unsigned short* dhi = Whi + r*528 + c0;
    unsigned short* dlo = Wlo + r*528 + c0;
    #pragma unroll 4
    for (int i=0;i<32;++i){
      float4 v = *(const float4*)(src + i*4);
      ushort4 hi, lo;
      hi.x=bfhi_(v.x); lo.x=bfhi_(v.x-bf2f_(hi.x));
      hi.y=bfhi_(v.y); lo.y=bfhi_(v.y-bf2f_(hi.y));
      hi.z=bfhi_(v.z); lo.z=bfhi_(v.z-bf2f_(hi.z));
      hi.w=bfhi_(v.w); lo.w=bfhi_(v.w-bf2f_(hi.w));
      *(ushort4*)(dhi + i*4) = hi;
      *(ushort4*)(dlo + i*4) = lo;
    }
  }

  const bool live = (lane < 32) && ((lane & 15) < 8);
  int bb = lane & 15;                               // batch (live lanes)
  int j0l = js*32 + wv*8 + (lane>>4)*4;             // 4 consecutive j (lane<32)
  float pgv[4] = {0,0,0,0}, pov[4] = {0,0,0,0};
  if (live){
    size_t prow = (size_t)(gb0 + bb)*1024;
    float4 g4 = *(const float4*)&P[prow + j0l];
    float4 o4 = *(const float4*)&P[prow + 512 + j0l];
    pgv[0]=g4.x; pgv[1]=g4.y; pgv[2]=g4.z; pgv[3]=g4.w;
    pov[0]=o4.x; pov[1]=o4.y; pov[2]=o4.z; pov[3]=o4.w;
  }
  const int arow_off = (wv*16 + (lane & 15))*528 + (lane>>4)*8;
  const int hcol = lane & 7;
  const int hk0 = (lane>>4)*8;

  for (int t=0; t<T_; ++t){
    int par = t & 1;
    if (t > 0 && tid < 16){                         // r11 poll: one 64B line
      unsigned* f = bgflags + tid;
      int guard = 0;
      while (__hip_atomic_load(f, __ATOMIC_RELAXED, __HIP_MEMORY_SCOPE_AGENT) < (unsigned)t){
        __builtin_amdgcn_s_sleep(4);
        if (++guard > (1<<22)) break;               // safety bail
      }
    }
    __syncthreads();                                // t=0: W staged; t>0: prev reads done

    // ---- stage h: thread tid owns u64 index tid (j-pair 2tid,2tid+1) for b=0..7
    const unsigned long long* hsrc =
      h_enc + (size_t)par*(B_*H_/2) + (size_t)gb0*256 + tid;
    unsigned long long v[8];
    #pragma unroll
    for (int b=0;b<8;++b)
      v[b] = __hip_atomic_load(&hsrc[(size_t)b*256], __ATOMIC_RELAXED, __HIP_MEMORY_SCOPE_AGENT);
    {
      unsigned* r0 = hb + (2*tid)*10;
      unsigned* r1 = hb + (2*tid+1)*10;
      *(uint4*)(r0+0) = make_uint4((unsigned)v[0],(unsigned)v[1],(unsigned)v[2],(unsigned)v[3]);
      *(uint4*)(r0+4) = make_uint4((unsigned)v[4],(unsigned)v[5],(unsigned)v[6],(unsigned)v[7]);
      *(uint2*)(r1+0) = make_uint2((unsigned)(v[0]>>32),(unsigned)(v[1]>>32));
      *(uint2*)(r1+2) = make_uint2((unsigned)(v[2]>>32),(unsigned)(v[3]>>32));
      *(uint2*)(r1+4) = make_uint2((unsigned)(v[4]>>32),(unsigned)(v[5]>>32));
      *(uint2*)(r1+6) = make_uint2((unsigned)(v[6]>>32),(unsigned)(v[7]>>32));
    }
    __syncthreads();

    // ---- MFMA: 16 k-steps x 3 split products
    f32x4 ac0 = {0,0,0,0}, ac1 = {0,0,0,0}, ac2 = {0,0,0,0};
    #pragma unroll
    for (int kc=0; kc<16; ++kc){
      bf16x8 bh, bl;
      #pragma unroll
      for (int e=0;e<8;++e){
        unsigned u = hb[(kc*32 + hk0 + e)*10 + hcol];
        bh[e] = (short)(u & 0xFFFFu);
        bl[e] = (short)(u >> 16);
      }
      bf16x8 ah = *(const bf16x8*)(Whi + arow_off + kc*32);
      bf16x8 al = *(const bf16x8*)(Wlo + arow_off + kc*32);
      ac0 = __builtin_amdgcn_mfma_f32_16x16x32_bf16(ah, bh, ac0, 0, 0, 0);
      ac1 = __builtin_amdgcn_mfma_f32_16x16x32_bf16(ah, bl, ac1, 0, 0, 0);
      ac2 = __builtin_amdgcn_mfma_f32_16x16x32_bf16(al, bh, ac2, 0, 0, 0);
    }
    float accv[4], oov[4];
    #pragma unroll
    for (int r=0;r<4;++r) accv[r] = ac0[r] + ac1[r] + ac2[r];
    #pragma unroll
    for (int r=0;r<4;++r) oov[r] = __shfl_xor(accv[r], 32, 64);  // lanes<32 get oo

    if (live){
      float h[4];
      #pragma unroll
      for (int r=0;r<4;++r){
        float gg = accv[r] + pgv[r];
        float oo = oov[r]  + pov[r];
        h[r] = sigm_(oo)*tanh_(tanh_(gg));
      }
      unsigned short p0h=bfhi_(h[0]), p0l=bfhi_(h[0]-bf2f_(p0h));
      unsigned short p1h=bfhi_(h[1]), p1l=bfhi_(h[1]-bf2f_(p1h));
      unsigned short p2h=bfhi_(h[2]), p2l=bfhi_(h[2]-bf2f_(p2h));
      unsigned short p3h=bfhi_(h[3]), p3l=bfhi_(h[3]-bf2f_(p3h));
      unsigned long long u0 = (unsigned long long)p0h | ((unsigned long long)p0l<<16)
                            | ((unsigned long long)p1h<<32) | ((unsigned long long)p1l<<48);
      unsigned long long u1 = (unsigned long long)p2h | ((unsigned long long)p2l<<16)
                            | ((unsigned long long)p3h<<32) | ((unsigned long long)p3l<<48);
      unsigned long long* dst =
        h_enc + (size_t)(1-par)*(B_*H_/2) + (size_t)(gb0 + bb)*256 + (j0l>>1);
      __hip_atomic_store(dst,   u0, __ATOMIC_RELAXED, __HIP_MEMORY_SCOPE_AGENT);
      __hip_atomic_store(dst+1, u1, __ATOMIC_RELAXED, __HIP_MEMORY_SCOPE_AGENT);
      if (t+1 < T_){                                // prefetch next-step P
        size_t prow = ((size_t)(t+1)*B_ + gb0 + bb)*1024;
        float4 g4 = *(const float4*)&P[prow + j0l];
        float4 o4 = *(const float4*)&P[prow + 512 + j0l];
        pgv[0]=g4.x; pgv[1]=g4.y; pgv[2]=g4.z; pgv[3]=g4.w;
        pov[0]=o4.x; pov[1]=o4.y; pov[2]=o4.z; pov[3]=o4.w;
      }
    }
    __syncthreads();   // per-wave vmcnt(0): h stores visible before flag
    if (t+1 < T_ && tid == 0)
      __hip_atomic_store(bgflags + js, (unsigned)(t+1),
                         __ATOMIC_RELAXED, __HIP_MEMORY_SCOPE_AGENT);
  }
}

// ---------------- classifier: out = hT @ w_out.T + b_out (hT = packed h_enc par-0) --
__global__ __launch_bounds__(256) void k_cls(
  const unsigned long long* __restrict__ h_enc, const float* __restrict__ w_out,
  const float* __restrict__ b_out, float* __restrict__ out)
{
  __shared__ float wt[32*68];     // [k][l] k-major
  __shared__ float htl[32*132];   // [k][b]
  int l0 = blockIdx.x * 64;       // 625 blocks
  int tid = threadIdx.x;
  int lq = tid >> 4, bq = tid & 15;
  float acc[4][8] = {};
  for (int kc=0; kc<16; ++kc){
    int k0 = kc*32;
    __syncthreads();
    #pragma unroll
    for (int it=0; it<2; ++it){   // w_out tile via float4
      int f = it*256 + tid;       // 0..511
      int l = f >> 3, k4 = (f & 7)*4;
      float4 v = *(const float4*)&w_out[(size_t)(l0+l)*H_ + k0 + k4];
      wt[(k4+0)*68 + l] = v.x; wt[(k4+1)*68 + l] = v.y;
      wt[(k4+2)*68 + l] = v.z; wt[(k4+3)*68 + l] = v.w;
    }
    #pragma unroll
    for (int it=0; it<4; ++it){   // hT tile: 2 u64 = 4 k-cols, decode hi+lo
      int f = it*256 + tid;       // 0..1023
      int b = f >> 3, k4 = (f & 7)*4;
      uint4 v = *(const uint4*)&h_enc[(size_t)b*256 + ((k0 + k4) >> 1)];
      htl[(k4+0)*132 + b] = decp_(v.x);
      htl[(k4+1)*132 + b] = decp_(v.y);
      htl[(k4+2)*132 + b] = decp_(v.z);
      htl[(k4+3)*132 + b] = decp_(v.w);
    }
    __syncthreads();
    #pragma unroll 4
    for (int k=0;k<32;++k){
      float4 w4 = *(const float4*)&wt[k*68 + lq*4];
      float4 h0 = *(const float4*)&htl[k*132 + bq*8];
      float4 h1 = *(const float4*)&htl[k*132 + bq*8 + 4];
      float wv[4] = {w4.x,w4.y,w4.z,w4.w};
      float hv[8] = {h0.x,h0.y,h0.z,h0.w,h1.x,h1.y,h1.z,h1.w};
      #pragma unroll
      for (int m=0;m<4;++m)
        #pragma unroll
        for (int i=0;i<8;++i) acc[m][i] = fmaf(wv[m], hv[i], acc[m][i]);
    }
  }
  int l = l0 + lq*4;
  float4 bo = *(const float4*)&b_out[l];
  #pragma unroll
  for (int i=0;i<8;++i){
    int b = bq*8 + i;
    float4 o4;
    o4.x = acc[0][i] + bo.x; o4.y = acc[1][i] + bo.y;
    o4.z = acc[2][i] + bo.z; o4.w = acc[3][i] + bo.w;
    *(float4*)&out[(size_t)b*L_ + l] = o4;
  }
}

extern "C" void kernel_launch(void* const* d_in, const int* in_sizes, int n_in,
                              void* d_out, int out_size, void* d_ws, size_t ws_size,
                              hipStream_t stream) {
  const int*   batch_l = (const int*)  d_in[0];
  const float* t_ld    = (const float*)d_in[1];
  const float* t_hd    = (const float*)d_in[2];
  const int*   t_l     = (const int*)  d_in[3];
  const int*   t_h     = (const int*)  d_in[4];
  const float* d_ld    = (const float*)d_in[5];
  const float* d_hd    = (const float*)d_in[6];
  const int*   d_l     = (const int*)  d_in[7];
  const int*   d_h     = (const int*)  d_in[8];
  const float* embed_l = (const float*)d_in[9];
  const float* embed_s = (const float*)d_in[10];
  const float* embed_q = (const float*)d_in[11];
  const float* w_ih    = (const float*)d_in[12];
  const float* w_hh    = (const float*)d_in[13];
  const float* w_s     = (const float*)d_in[14];
  const float* w_q     = (const float*)d_in[15];
  const float* b_ih    = (const float*)d_in[16];
  const float* b_hh    = (const float*)d_in[17];
  const float* w_out   = (const float*)d_in[18];
  const float* b_out   = (const float*)d_in[19];
  float* out = (float*)d_out;

  // workspace layout (float offsets; h_enc u64 at even-float offset -> 16B aligned)
  float* ws = (float*)d_ws;
  const size_t P_off   = 0;                         // 13107200 f
  const size_t h_off   = 13107200;                  // 131072 f = 65536 u64 (2 parities)
  const size_t es_off  = h_off + 131072;            // 5120 f
  const size_t eq_off  = es_off + 5120;             // 5120 f
  const size_t flg_off = eq_off + 5120;             // 256 u32
  const size_t whi_off = flg_off + 256;             // 1024*256 ushort = 131072 f
  const size_t wlo_off = whi_off + 131072;
  const size_t need_base = (flg_off + 256)*4 + 64;
  const size_t need_full = (wlo_off + 131072)*4 + 64;
  if (ws_size < need_base) return;

  float* P        = ws + P_off;
  unsigned long long* h_enc = (unsigned long long*)(ws + h_off);
  float* es_proj  = ws + es_off;
  float* eq_proj  = ws + eq_off;
  unsigned* flags = (unsigned*)(ws + flg_off);
  unsigned short* Whi = (unsigned short*)(ws + whi_off);
  unsigned short* Wlo = (unsigned short*)(ws + wlo_off);

  hipFuncSetAttribute(reinterpret_cast<const void*>(k_rec),
                      hipFuncAttributeMaxDynamicSharedMemorySize, 155648);

  k_init<<<297, 256, 0, stream>>>(h_enc, flags, embed_s, embed_q, w_s, w_q,
                                  es_proj, eq_proj);
  if (ws_size >= need_full){
    k_conv_w<<<256, 256, 0, stream>>>(w_ih, Whi, Wlo);
    k_phase1<<<dim3(200,16), 256, 0, stream>>>(batch_l, embed_l, Whi, Wlo,
        b_ih, b_hh, t_ld, t_hd, t_l, t_h, d_ld, d_hd, d_l, d_h, es_proj, eq_proj, P);
  } else {
    return;  // workspace fallback not expected (ws was sufficient in r17-r19)
  }
  k_rec<<<256, 256, 155648, stream>>>(w_hh, P, h_enc, flags);
  k_cls<<<625, 256, 0, stream>>>(h_enc, w_out, b_out, out);
}